// Round 22
// baseline (228.251 us; speedup 1.0000x reference)
//
#include <hip/hip_runtime.h>
#include <math.h>

#define NN 16384      // H*W per image
#define WW 128
#define CDIM 192
#define HIDD 510
#define BB 2

typedef unsigned short ushort_t;
using short8 = __attribute__((ext_vector_type(8))) short;
using f32x4  = __attribute__((ext_vector_type(4))) float;

__device__ __forceinline__ float bf2f(ushort_t u) {
    union { unsigned int i; float f; } v; v.i = ((unsigned int)u) << 16; return v.f;
}
__device__ __forceinline__ ushort_t f2bf(float f) {
    union { unsigned int i; float f; } v; v.f = f;
    unsigned int i = v.i;
    return (ushort_t)((i + 0x7fffu + ((i >> 16) & 1u)) >> 16);  // RNE
}
// d = a.bf16[0]*b.bf16[0] + a.bf16[1]*b.bf16[1] + c   (V_DOT2_F32_BF16)
__device__ __forceinline__ float dot2bf(unsigned int a, unsigned int b, float c) {
    float d;
    asm("v_dot2_f32_bf16 %0, %1, %2, %3" : "=v"(d) : "v"(a), "v"(b), "v"(c));
    return d;
}
// pack two f32 -> bf16x2 word (lo = a, hi = b)
__device__ __forceinline__ unsigned int cvtpk(float a, float b) {
    unsigned int r;
    asm("v_cvt_pk_bf16_f32 %0, %1, %2" : "=v"(r) : "v"(a), "v"(b));
    return r;
}

// -------- ALL weight conversions in one kernel (range-dispatched) ----------
// appended: dwP [2][4 pairs][512] bf16x2-words (8192 ushorts),
//           dwS [2][512] bf16 singles for tap 8 (1024 ushorts)
#define CW_TOTAL 474624
__global__ __launch_bounds__(256) void convw_all(
    const float* __restrict__ qkv_w, const float* __restrict__ off_w,
    const float* __restrict__ proj_w, const float* __restrict__ pi_w,
    const float* __restrict__ po_w,  const float* __restrict__ dw_w,
    ushort_t* __restrict__ ws)
{
    int idx = blockIdx.x * 256 + threadIdx.x;
    if (idx >= CW_TOTAL) return;
    int i = idx;
    if (i < 110592) { ws[idx] = f2bf(qkv_w[i]); return; }
    i -= 110592;
    if (i < 13824)  { ws[idx] = f2bf(off_w[i]); return; }
    i -= 13824;
    if (i < 36864)  { ws[idx] = f2bf(proj_w[i]); return; }
    i -= 36864;
    if (i < 196608) {
        int o = i / 192, k = i - o * 192;
        bool zero = (o == 510) || (o == 511) || (o >= 1022);
        int so = (o < 510) ? o : o - 2;
        ws[idx] = zero ? (ushort_t)0 : f2bf(pi_w[(size_t)so * 192 + k]);
        return;
    }
    i -= 196608;
    if (i < 98304) {
        int o = i >> 9, k = i & 511;
        ws[idx] = (k < HIDD) ? f2bf(po_w[(size_t)o * HIDD + k]) : (ushort_t)0;
        return;
    }
    i -= 98304;
    if (i < 9216) {   // dwT: [9][2][512] (edge path)
        int p = i >> 10, c = i & 1023;
        int half = c >> 9, cc = c & 511;
        ws[idx] = (cc < HIDD) ? f2bf(dw_w[(size_t)(half * HIDD + cc) * 9 + p]) : (ushort_t)0;
        return;
    }
    i -= 9216;
    if (i < 8192) {   // dwP: pair-packed; wi = i>>1, lo/hi = i&1
        int wi = i >> 1, hl = i & 1;
        int h = wi >> 11, rem = wi & 2047;
        int k = rem >> 9, c = rem & 511;
        int pos = 2 * k + hl;
        ws[idx] = (c < HIDD) ? f2bf(dw_w[(size_t)(h * HIDD + c) * 9 + pos]) : (ushort_t)0;
        return;
    }
    i -= 8192;
    {   // dwS: tap-8 singles [2][512]
        int h = i >> 9, c = i & 511;
        ws[idx] = (c < HIDD) ? f2bf(dw_w[(size_t)(h * HIDD + c) * 9 + 8]) : (ushort_t)0;
    }
}

// ---------------- MFMA GEMM: acc[o,n] = sum_k Wb[o,k]*X_pm[n,k] ------------
// XMODE 0: X pixel-major [N][KT] bf16.
// XMODE 1: X = 4 planes [4][N][48] (KT=192), attn plane-major output.
// XMODE 2: fused BiasFree-LN1 staging from f32 channel-major x (in R, stride
//          xzs, weights in W2). NSPLIT = BDIM/NTILE channel-splits.
// MODE 0: bf16 out at ((o/48)*NN+n)*48 + o%48      (qkv planes)
// MODE 2: f32  out at o*NN+n, += R                 (po epilogue)
// MODE 3: bf16 out at n*1024 + o                   (pi -> t)
// MODE 4: f32  out at o*NN+n, += R; fused LN -> bf16 XN2[n][192] (192 thr)
// MODE 5: merged qkv+off: obase<576 -> MODE0 to Yv; >=576 -> offsets to XN2
// NOTE: two attempts at a write-coalesced MODE 3 epilogue (LDS transpose,
// shfl transpose) produced NaNs with no identifiable defect by inspection;
// the scatter epilogue below is the verified-correct form. Future work:
// isolate with a single-kernel debug harness before re-attempting.
template<int MODE, int XMODE, int KT, int KP, int NTILE, int BDIM = 256>
__global__ __launch_bounds__(BDIM) void gemm_mfma(
    const ushort_t* __restrict__ Wb,
    const ushort_t* __restrict__ X,
    const float* __restrict__ R,
    void* __restrict__ Yv,
    int O,
    size_t xzs, size_t yzs, size_t rzs,
    const float* __restrict__ W2, ushort_t* __restrict__ XN2)
{
    extern __shared__ ushort_t Xt[];   // [NTILE][KP]
    constexpr int NSEG = KT >> 3;
    constexpr int NFR  = NTILE / 16;
    int tid = threadIdx.x;
    constexpr int nt = BDIM;
    constexpr int nw = BDIM >> 6;
    int z   = blockIdx.z;
    int n0  = blockIdx.x * NTILE;

    if constexpr (XMODE == 0 || XMODE == 1) {
        const ushort_t* Xb = X + (size_t)z * xzs;
        for (int u = tid; u < NTILE * NSEG; u += nt) {
            int r = u / NSEG, seg = u - r * NSEG;
            const ushort_t* src;
            if (XMODE == 0) {
                src = Xb + (size_t)(n0 + r) * KT + seg * 8;
            } else {
                int plane = seg / 6, w8 = seg - plane * 6;
                src = Xb + ((size_t)plane * NN + n0 + r) * 48 + w8 * 8;
            }
            *(uint4*)&Xt[(size_t)r * KP + seg * 8] = *(const uint4*)src;
        }
    } else {
        // XMODE 2: fused LN1. BDIM = NSPLIT * NTILE threads.
        constexpr int NSPLIT = BDIM / NTILE;
        constexpr int CPS    = CDIM / NSPLIT;
        __shared__ float lnr[NSPLIT][NTILE][2];
        int px = tid % NTILE, cs = tid / NTILE;
        const float* xp = R + (size_t)z * xzs + (size_t)(cs * CPS) * NN + n0 + px;
        float s = 0.f, s2 = 0.f;
        for (int cc = 0; cc < CPS; ++cc) {
            float v = xp[(size_t)cc * NN];
            s += v; s2 += v * v;
        }
        lnr[cs][px][0] = s; lnr[cs][px][1] = s2;
        __syncthreads();
        float ts = 0.f, ts2 = 0.f;
        #pragma unroll
        for (int q = 0; q < NSPLIT; ++q) { ts += lnr[q][px][0]; ts2 += lnr[q][px][1]; }
        float mu  = ts * (1.f / 192.f);
        float rs_ = rsqrtf(ts2 * (1.f / 192.f) - mu * mu + 1e-5f);
        for (int cc = 0; cc < CPS; cc += 2) {
            float v0 = xp[(size_t)cc * NN]       * rs_ * W2[cs * CPS + cc];
            float v1 = xp[(size_t)(cc + 1) * NN] * rs_ * W2[cs * CPS + cc + 1];
            unsigned int pk = (unsigned int)f2bf(v0) | ((unsigned int)f2bf(v1) << 16);
            *(unsigned int*)&Xt[(size_t)px * KP + cs * CPS + cc] = pk;
        }
    }
    __syncthreads();

    int w = tid >> 6, l = tid & 63;
    int o0w = blockIdx.y * (nw * 64) + w * 64;
    if (o0w >= O) return;

    int lrow = l & 15;
    int lk   = (l >> 4) * 8;

    f32x4 acc[4][NFR] = {};

    #pragma unroll
    for (int kk0 = 0; kk0 < KT; kk0 += 32) {
        short8 bfr[NFR];
        #pragma unroll
        for (int ni = 0; ni < NFR; ++ni)
            bfr[ni] = *(const short8*)&Xt[(size_t)(ni * 16 + lrow) * KP + kk0 + lk];
        short8 afr[4];
        #pragma unroll
        for (int mi = 0; mi < 4; ++mi) {
            int orow = o0w + mi * 16 + lrow;
            if (orow < O)
                afr[mi] = *(const short8*)(Wb + (size_t)orow * KT + kk0 + lk);
            else
                afr[mi] = short8{0,0,0,0,0,0,0,0};
        }
        #pragma unroll
        for (int mi = 0; mi < 4; ++mi)
            #pragma unroll
            for (int ni = 0; ni < NFR; ++ni)
                acc[mi][ni] = __builtin_amdgcn_mfma_f32_16x16x32_bf16(
                    afr[mi], bfr[ni], acc[mi][ni], 0, 0, 0);
    }

    int orow0 = (l >> 4) * 4;

    if constexpr (MODE == 4) {
        __shared__ float red[3][NTILE][2];
        float s[NFR] = {}, s2[NFR] = {};
        #pragma unroll
        for (int mi = 0; mi < 4; ++mi)
            #pragma unroll
            for (int ni = 0; ni < NFR; ++ni) {
                int n = n0 + ni * 16 + lrow;
                int obase = o0w + mi * 16 + orow0;
                #pragma unroll
                for (int r = 0; r < 4; ++r) {
                    float v = acc[mi][ni][r] +
                              R[(size_t)z * rzs + (size_t)(obase + r) * NN + n];
                    acc[mi][ni][r] = v;
                    s[ni] += v; s2[ni] += v * v;
                }
            }
        #pragma unroll
        for (int ni = 0; ni < NFR; ++ni) {
            s[ni]  += __shfl_xor(s[ni], 16);  s[ni]  += __shfl_xor(s[ni], 32);
            s2[ni] += __shfl_xor(s2[ni], 16); s2[ni] += __shfl_xor(s2[ni], 32);
        }
        if (l < 16) {
            #pragma unroll
            for (int ni = 0; ni < NFR; ++ni) {
                red[w][ni * 16 + l][0] = s[ni];
                red[w][ni * 16 + l][1] = s2[ni];
            }
        }
        __syncthreads();
        float rsv[NFR];
        #pragma unroll
        for (int ni = 0; ni < NFR; ++ni) {
            int nl = ni * 16 + lrow;
            float ts  = red[0][nl][0] + red[1][nl][0] + red[2][nl][0];
            float ts2 = red[0][nl][1] + red[1][nl][1] + red[2][nl][1];
            float mu  = ts * (1.f / 192.f);
            float var = ts2 * (1.f / 192.f) - mu * mu;
            rsv[ni] = rsqrtf(var + 1e-5f);
        }
        #pragma unroll
        for (int mi = 0; mi < 4; ++mi)
            #pragma unroll
            for (int ni = 0; ni < NFR; ++ni) {
                int n = n0 + ni * 16 + lrow;
                int obase = o0w + mi * 16 + orow0;
                #pragma unroll
                for (int r = 0; r < 4; ++r)
                    ((float*)Yv)[(size_t)z * yzs + (size_t)(obase + r) * NN + n]
                        = acc[mi][ni][r];
                float rs_ = rsv[ni];
                unsigned int lo =
                    (unsigned int)f2bf(acc[mi][ni][0] * rs_ * W2[obase])
                  | ((unsigned int)f2bf(acc[mi][ni][1] * rs_ * W2[obase + 1]) << 16);
                unsigned int hi =
                    (unsigned int)f2bf(acc[mi][ni][2] * rs_ * W2[obase + 2])
                  | ((unsigned int)f2bf(acc[mi][ni][3] * rs_ * W2[obase + 3]) << 16);
                *(uint2*)(XN2 + (size_t)z * ((size_t)NN * CDIM)
                          + (size_t)n * CDIM + obase) = make_uint2(lo, hi);
            }
    } else {
        #pragma unroll
        for (int mi = 0; mi < 4; ++mi) {
            #pragma unroll
            for (int ni = 0; ni < NFR; ++ni) {
                int n = n0 + ni * 16 + lrow;
                int obase = o0w + mi * 16 + orow0;
                float v0 = acc[mi][ni][0], v1 = acc[mi][ni][1];
                float v2 = acc[mi][ni][2], v3 = acc[mi][ni][3];
                if (MODE == 0 || MODE == 3) {
                    if (obase >= O) continue;
                    unsigned int lo = (unsigned int)f2bf(v0) | ((unsigned int)f2bf(v1) << 16);
                    unsigned int hi = (unsigned int)f2bf(v2) | ((unsigned int)f2bf(v3) << 16);
                    size_t base = (MODE == 0)
                        ? ((size_t)(obase / 48) * NN + n) * 48 + (obase % 48)
                        : (size_t)n * 1024 + obase;
                    *(uint2*)((ushort_t*)Yv + (size_t)z * yzs + base) = make_uint2(lo, hi);
                } else if (MODE == 5) {
                    if (obase < 576) {
                        unsigned int lo = (unsigned int)f2bf(v0) | ((unsigned int)f2bf(v1) << 16);
                        unsigned int hi = (unsigned int)f2bf(v2) | ((unsigned int)f2bf(v3) << 16);
                        size_t base = ((size_t)(obase / 48) * NN + n) * 48 + (obase % 48);
                        *(uint2*)((ushort_t*)Yv + (size_t)z * yzs + base) = make_uint2(lo, hi);
                    } else {
                        float vv[4] = {v0, v1, v2, v3};
                        #pragma unroll
                        for (int r = 0; r < 4; ++r) {
                            int o = obase + r - 576;
                            if (o >= 0 && o < 72)
                                XN2[(size_t)z * rzs +
                                    ((size_t)(o / 18) * NN + n) * 24 + (o % 18)] = f2bf(vv[r]);
                        }
                    }
                } else {  // MODE 2
                    float vv[4] = {v0, v1, v2, v3};
                    #pragma unroll
                    for (int r = 0; r < 4; ++r) {
                        int o = obase + r;
                        if (o < O) {
                            size_t idx = (size_t)o * NN + n;
                            ((float*)Yv)[(size_t)z * yzs + idx] = vv[r] + R[(size_t)z * rzs + idx];
                        }
                    }
                }
            }
        }
    }
}

// ------------- deformable attention, single dispatch, XCD-bijective --------
__global__ __launch_bounds__(256, 2) void attn_kernel(
    const ushort_t* __restrict__ qkv_pm,   // [B][12][N][48]
    const ushort_t* __restrict__ off_pm,   // [B][4][N][24]
    const float* __restrict__ rpb,         // [4,9]
    ushort_t* __restrict__ out_pl)         // [B][4][N][48]
{
    int bid = blockIdx.x;                       // 0..2047
    int lin = (bid & 7) * 256 + (bid >> 3);
    int c   = lin >> 7;                         // 0..15
    int b   = c >> 3;
    int h   = (c >> 1) & 3;
    int half= c & 1;
    int r   = lin & 127;
    int py  = half * 64 + (r >> 1);
    int tid = threadIdx.x;
    int px  = (r & 1) * 64 + (tid >> 2);
    int s   = tid & 3;
    int n   = py * WW + px;

    const ushort_t* qkvB = qkv_pm + (size_t)b * 12 * NN * 48;
    const ushort_t* offB = off_pm + (size_t)b * 4 * NN * 24;
    ushort_t*       outB = out_pl + (size_t)b * 4 * NN * 48;

    union { uint4 u[3]; ushort_t v[24]; } ob;
    {
        const ushort_t* op = offB + ((size_t)h * NN + n) * 24;
        ob.u[0] = *(const uint4*)op;
        ob.u[1] = *(const uint4*)(op + 8);
        ob.u[2] = *(const uint4*)(op + 16);
    }

    int   baseu[9], dxu[9], dyu[9];
    float wyA[9], wxA[9];
    #pragma unroll
    for (int kpt = 0; kpt < 9; ++kpt) {
        float oy = bf2f(ob.v[kpt * 2 + 0]);
        float ox = bf2f(ob.v[kpt * 2 + 1]);
        float cy = fminf(fmaxf((float)(py + (kpt / 3) - 1) + oy, 0.f), 127.f);
        float cx = fminf(fmaxf((float)(px + (kpt % 3) - 1) + ox, 0.f), 127.f);
        float y0f = floorf(cy), x0f = floorf(cx);
        wyA[kpt] = cy - y0f; wxA[kpt] = cx - x0f;
        int y0 = (int)y0f, x0 = (int)x0f;
        baseu[kpt] = (y0 * WW + x0) * 48;
        dxu[kpt]   = (x0 < 127) ? 48 : 0;
        dyu[kpt]   = (y0 < 127) ? (WW * 48) : 0;
    }

    const ushort_t* qrow  = qkvB + ((size_t)h * NN + n) * 48;
    const ushort_t* kbase = qkvB + ((size_t)(4 + h) * NN) * 48;
    const ushort_t* vbase = qkvB + ((size_t)(8 + h) * NN) * 48;
    int co0 = s * 12;

    unsigned int qp[6];
    {
        uint2 a = *(const uint2*)(qrow + co0);
        uint2 bq = *(const uint2*)(qrow + co0 + 4);
        uint2 cq = *(const uint2*)(qrow + co0 + 8);
        qp[0] = a.x; qp[1] = a.y; qp[2] = bq.x; qp[3] = bq.y; qp[4] = cq.x; qp[5] = cq.y;
    }

    float logits[9];
    #pragma unroll
    for (int kpt = 0; kpt < 9; ++kpt) {
        const ushort_t* kb = kbase + baseu[kpt] + co0;
        int du = dxu[kpt], dv = dyu[kpt];
        float d0 = 0.f, d1 = 0.f, d2 = 0.f, d3 = 0.f;
        #pragma unroll
        for (int ch = 0; ch < 3; ++ch) {
            const ushort_t* p = kb + ch * 4;
            uint2 k0 = *(const uint2*)p;
            uint2 k1 = *(const uint2*)(p + du);
            uint2 k2 = *(const uint2*)(p + dv);
            uint2 k3 = *(const uint2*)(p + dv + du);
            d0 = dot2bf(k0.x, qp[2 * ch], d0); d0 = dot2bf(k0.y, qp[2 * ch + 1], d0);
            d1 = dot2bf(k1.x, qp[2 * ch], d1); d1 = dot2bf(k1.y, qp[2 * ch + 1], d1);
            d2 = dot2bf(k2.x, qp[2 * ch], d2); d2 = dot2bf(k2.y, qp[2 * ch + 1], d2);
            d3 = dot2bf(k3.x, qp[2 * ch], d3); d3 = dot2bf(k3.y, qp[2 * ch + 1], d3);
        }
        float wy = wyA[kpt], wx = wxA[kpt];
        float iy = 1.f - wy, ix = 1.f - wx;
        logits[kpt] = fmaf(wy * wx, d3, fmaf(wy * ix, d2,
                      fmaf(iy * wx, d1, iy * ix * d0)));
    }

    #pragma unroll
    for (int kpt = 0; kpt < 9; ++kpt) {
        float v = logits[kpt];
        v += __shfl_xor(v, 1);
        v += __shfl_xor(v, 2);
        logits[kpt] = v * 0.14433756729740643f + rpb[h * 9 + kpt];
    }
    float m = logits[0];
    #pragma unroll
    for (int i = 1; i < 9; ++i) m = fmaxf(m, logits[i]);
    float ssum = 0.f;
    #pragma unroll
    for (int i = 0; i < 9; ++i) { logits[i] = __expf(logits[i] - m); ssum += logits[i]; }
    float inv = 1.f / ssum;

    float oacc[12] = {};
    #pragma unroll
    for (int kpt = 0; kpt < 9; ++kpt) {
        float wy = wyA[kpt], wx = wxA[kpt];
        float iy = 1.f - wy, ix = 1.f - wx;
        float a = logits[kpt] * inv;
        unsigned int w01 = cvtpk(a * iy * ix, a * iy * wx);
        unsigned int w23 = cvtpk(a * wy * ix, a * wy * wx);
        const ushort_t* vb = vbase + baseu[kpt] + co0;
        int du = dxu[kpt], dv = dyu[kpt];
        #pragma unroll
        for (int ch = 0; ch < 3; ++ch) {
            const ushort_t* p = vb + ch * 4;
            uint2 A = *(const uint2*)p;
            uint2 Bv = *(const uint2*)(p + du);
            uint2 Cv = *(const uint2*)(p + dv);
            uint2 Dv = *(const uint2*)(p + dv + du);
            unsigned int T0 = __builtin_amdgcn_perm(A.x, Bv.x, 0x01000504u);
            unsigned int T1 = __builtin_amdgcn_perm(A.x, Bv.x, 0x03020706u);
            unsigned int U0 = __builtin_amdgcn_perm(Cv.x, Dv.x, 0x01000504u);
            unsigned int U1 = __builtin_amdgcn_perm(Cv.x, Dv.x, 0x03020706u);
            oacc[ch * 4 + 0] = dot2bf(U0, w23, dot2bf(T0, w01, oacc[ch * 4 + 0]));
            oacc[ch * 4 + 1] = dot2bf(U1, w23, dot2bf(T1, w01, oacc[ch * 4 + 1]));
            T0 = __builtin_amdgcn_perm(A.y, Bv.y, 0x01000504u);
            T1 = __builtin_amdgcn_perm(A.y, Bv.y, 0x03020706u);
            U0 = __builtin_amdgcn_perm(Cv.y, Dv.y, 0x01000504u);
            U1 = __builtin_amdgcn_perm(Cv.y, Dv.y, 0x03020706u);
            oacc[ch * 4 + 2] = dot2bf(U0, w23, dot2bf(T0, w01, oacc[ch * 4 + 2]));
            oacc[ch * 4 + 3] = dot2bf(U1, w23, dot2bf(T1, w01, oacc[ch * 4 + 3]));
        }
    }

    ushort_t* orow = outB + ((size_t)h * NN + n) * 48 + co0;
    #pragma unroll
    for (int ch = 0; ch < 3; ++ch) {
        unsigned int lo = (unsigned int)f2bf(oacc[ch * 4 + 0])
                        | ((unsigned int)f2bf(oacc[ch * 4 + 1]) << 16);
        unsigned int hi = (unsigned int)f2bf(oacc[ch * 4 + 2])
                        | ((unsigned int)f2bf(oacc[ch * 4 + 3]) << 16);
        *(uint2*)(orow + ch * 4) = make_uint2(lo, hi);
    }
}

// ------- depthwise 3x3 (both halves) + exact-GELU gate; 8 ch / thread ------
// Wave = one pixel -> interior/edge branch is wave-uniform.
// Interior: 4 tap-pairs via v_perm + prepacked bf16x2 weights + dot2.
__global__ __launch_bounds__(256) void dwgate_kernel(
    const ushort_t* __restrict__ t_pm,
    const ushort_t* __restrict__ wT,    // [9][2][512] (edge path)
    const unsigned int* __restrict__ wP,// [2][4][512] packed pairs
    const ushort_t* __restrict__ wS,    // [2][512] tap-8 singles
    ushort_t* __restrict__ g_pm)
{
    int b = blockIdx.y;
    const ushort_t* tB = t_pm + (size_t)b * NN * 1024;
    ushort_t*       gB = g_pm + (size_t)b * NN * 512;
    int bid = blockIdx.x;                        // 4096
    int lin = (bid & 7) * 512 + (bid >> 3);      // XCD-contiguous
    int idx = lin * 256 + threadIdx.x;           // over N*64
    int c0 = (idx & 63) * 8;
    int n  = idx >> 6;
    int y = n >> 7, x = n & 127;
    float a1[8] = {}, a2[8] = {};

    if (x >= 1 && x <= 126 && y >= 1 && y <= 126) {
        // ---- interior fast path: 4 pairs + 1 single per half ----
        const ushort_t* trow[9];
        #pragma unroll
        for (int p = 0; p < 9; ++p)
            trow[p] = tB + (size_t)((y + p / 3 - 1) * WW + (x + p % 3 - 1)) * 1024;
        #pragma unroll
        for (int hlf = 0; hlf < 2; ++hlf) {
            float* aa = hlf ? a2 : a1;
            int cb = c0 + hlf * 512;
            #pragma unroll
            for (int k = 0; k < 4; ++k) {
                uint4 A = *(const uint4*)(trow[2 * k] + cb);
                uint4 Bv = *(const uint4*)(trow[2 * k + 1] + cb);
                uint4 W0 = *(const uint4*)(wP + (size_t)(hlf * 4 + k) * 512 + c0);
                uint4 W1 = *(const uint4*)(wP + (size_t)(hlf * 4 + k) * 512 + c0 + 4);
                unsigned int Av[4] = {A.x, A.y, A.z, A.w};
                unsigned int Bw[4] = {Bv.x, Bv.y, Bv.z, Bv.w};
                unsigned int Wv[8] = {W0.x, W0.y, W0.z, W0.w, W1.x, W1.y, W1.z, W1.w};
                #pragma unroll
                for (int d = 0; d < 4; ++d) {
                    unsigned int T0 = __builtin_amdgcn_perm(Av[d], Bw[d], 0x01000504u);
                    unsigned int T1 = __builtin_amdgcn_perm(Av[d], Bw[d], 0x03020706u);
                    aa[2 * d]     = dot2bf(T0, Wv[2 * d],     aa[2 * d]);
                    aa[2 * d + 1] = dot2bf(T1, Wv[2 * d + 1], aa[2 * d + 1]);
                }
            }
            {   // single tap 8 (dy=+1, dx=+1)
                short8 tv = *(const short8*)(trow[8] + cb);
                short8 wv = *(const short8*)(wS + hlf * 512 + c0);
                #pragma unroll
                for (int j = 0; j < 8; ++j)
                    aa[j] = fmaf(bf2f((ushort_t)tv[j]), bf2f((ushort_t)wv[j]), aa[j]);
            }
        }
    } else {
        // ---- edge path: original scalar taps with bounds checks ----
        #pragma unroll
        for (int dy = 0; dy < 3; ++dy) {
            int yy = y + dy - 1;
            if (yy < 0 || yy > 127) continue;
            #pragma unroll
            for (int dx = 0; dx < 3; ++dx) {
                int xx = x + dx - 1;
                if (xx < 0 || xx > 127) continue;
                int p = dy * 3 + dx;
                const ushort_t* tr = tB + (size_t)(yy * WW + xx) * 1024;
                short8 t1 = *(const short8*)(tr + c0);
                short8 t2 = *(const short8*)(tr + 512 + c0);
                short8 w1 = *(const short8*)(wT + p * 1024 + c0);
                short8 w2 = *(const short8*)(wT + p * 1024 + 512 + c0);
                #pragma unroll
                for (int j = 0; j < 8; ++j) {
                    a1[j] = fmaf(bf2f((ushort_t)t1[j]), bf2f((ushort_t)w1[j]), a1[j]);
                    a2[j] = fmaf(bf2f((ushort_t)t2[j]), bf2f((ushort_t)w2[j]), a2[j]);
                }
            }
        }
    }
    short8 o8;
    #pragma unroll
    for (int j = 0; j < 8; ++j) {
        float ge = 0.5f * a1[j] * (1.f + erff(a1[j] * 0.70710678118654752f));
        o8[j] = (short)f2bf(ge * a2[j]);
    }
    *(short8*)(gB + (size_t)n * 512 + c0) = o8;
}

extern "C" void kernel_launch(void* const* d_in, const int* in_sizes, int n_in,
                              void* d_out, int out_size, void* d_ws, size_t ws_size,
                              hipStream_t stream)
{
    const float* x      = (const float*)d_in[0];
    const float* ln1_w  = (const float*)d_in[1];
    const float* ln2_w  = (const float*)d_in[2];
    const float* qkv_w  = (const float*)d_in[3];
    const float* off_w  = (const float*)d_in[4];
    const float* rpb    = (const float*)d_in[5];
    const float* proj_w = (const float*)d_in[6];
    const float* pi_w   = (const float*)d_in[7];
    const float* dw_w   = (const float*)d_in[8];
    const float* po_w   = (const float*)d_in[9];
    float* out = (float*)d_out;

    // ---- workspace layout (ushort units), ~137 MB ----
    ushort_t* ws = (ushort_t*)d_ws;
    ushort_t* qkv_wb  = ws;                                   // 648*192 merged
    ushort_t* proj_wb = qkv_wb  + 648 * 192;
    ushort_t* pi_wb   = proj_wb + 192 * 192;
    ushort_t* po_wb   = pi_wb   + 1024 * 192;
    ushort_t* dwT     = po_wb   + 192 * 512;                  // 9*1024
    ushort_t* dwP     = dwT     + 9 * 1024;                   // 8192 (pair words)
    ushort_t* dwS     = dwP     + 8192;                       // 1024
    ushort_t* xn      = dwS     + 1024;                       // attn-out [2][4][N][48]
    ushort_t* qkvb    = xn      + (size_t)2 * NN * CDIM;      // [2][12][N][48] (also g)
    ushort_t* offb    = qkvb    + (size_t)2 * 12 * NN * 48;   // [2][4][N][24]
    ushort_t* t       = offb    + (size_t)2 * 4 * NN * 24;    // [2][N][1024]
    ushort_t* xn2     = t       + (size_t)2 * NN * 1024;      // [2][N][192]
    ushort_t* attn    = xn;
    ushort_t* g       = qkvb;

    dim3 blk(256);

    convw_all<<<dim3((CW_TOTAL + 255) / 256), blk, 0, stream>>>(
        qkv_w, off_w, proj_w, pi_w, po_w, dw_w, ws);

    const int shm64  = 64 * 200 * 2;        // 25600 B
    const int shm128 = 128 * 200 * 2;       // 51200 B
    const int shm512 = 64 * 520 * 2;        // 66560 B
    const size_t XN_S   = (size_t)NN * CDIM;
    const size_t QKV_S  = (size_t)12 * NN * 48;
    const size_t OFF_S  = (size_t)4 * NN * 24;
    const size_t APL_S  = (size_t)4 * NN * 48;
    const size_t T_S    = (size_t)NN * 1024;
    const size_t G_S    = (size_t)NN * 512;
    const size_t CM_S   = (size_t)CDIM * NN;

    // 1. qkv planes + offsets + FUSED LN1: 768-thread blocks
    gemm_mfma<5, 2, 192, 200, 64, 768><<<dim3(256, 1, 2), dim3(768), shm64, stream>>>(
        qkv_wb, nullptr, x, qkvb, 648, CM_S, QKV_S, OFF_S, ln1_w, offb);
    // 2. deformable attention
    attn_kernel<<<dim3(2048), blk, 0, stream>>>(qkvb, offb, rpb, attn);
    // 3. x1 = x + proj_wb @ attn -> d_out, fused LN2 -> xn2
    gemm_mfma<4, 1, 192, 200, 128, 192><<<dim3(128, 1, 2), dim3(192), shm128, stream>>>(
        proj_wb, attn, x, out, 192, APL_S, CM_S, CM_S, ln2_w, xn2);
    // 4. t = pi_wb @ xn2   (verified scatter epilogue)
    gemm_mfma<3, 0, 192, 200, 128, 512><<<dim3(128, 2, 2), dim3(512), shm128, stream>>>(
        pi_wb, xn2, nullptr, t, 1024, XN_S, T_S, 0, nullptr, nullptr);
    // 5. g = gelu(dw(t1)) * dw(t2)  (pair-packed interior path)
    dwgate_kernel<<<dim3(NN * 64 / 256, 2), blk, 0, stream>>>(
        t, dwT, (const unsigned int*)dwP, dwS, g);
    // 6. out = x1 + po_wb @ g
    gemm_mfma<2, 0, 512, 520, 64, 192><<<dim3(256, 1, 2), dim3(192), shm512, stream>>>(
        po_wb, g, out, out, 192, G_S, CM_S, CM_S, nullptr, nullptr);
}

// Round 23
// 225.543 us; speedup vs baseline: 1.0120x; 1.0120x over previous
//
#include <hip/hip_runtime.h>
#include <math.h>

#define NN 16384      // H*W per image
#define WW 128
#define CDIM 192
#define HIDD 510
#define BB 2

typedef unsigned short ushort_t;
using short8 = __attribute__((ext_vector_type(8))) short;
using f32x4  = __attribute__((ext_vector_type(4))) float;

__device__ __forceinline__ float bf2f(ushort_t u) {
    union { unsigned int i; float f; } v; v.i = ((unsigned int)u) << 16; return v.f;
}
__device__ __forceinline__ ushort_t f2bf(float f) {
    union { unsigned int i; float f; } v; v.f = f;
    unsigned int i = v.i;
    return (ushort_t)((i + 0x7fffu + ((i >> 16) & 1u)) >> 16);  // RNE
}
// d = a.bf16[0]*b.bf16[0] + a.bf16[1]*b.bf16[1] + c   (V_DOT2_F32_BF16)
__device__ __forceinline__ float dot2bf(unsigned int a, unsigned int b, float c) {
    float d;
    asm("v_dot2_f32_bf16 %0, %1, %2, %3" : "=v"(d) : "v"(a), "v"(b), "v"(c));
    return d;
}
// pack two f32 -> bf16x2 word (lo = a, hi = b)
__device__ __forceinline__ unsigned int cvtpk(float a, float b) {
    unsigned int r;
    asm("v_cvt_pk_bf16_f32 %0, %1, %2" : "=v"(r) : "v"(a), "v"(b));
    return r;
}

// -------- ALL weight conversions in one kernel (range-dispatched) ----------
// appended: dwP [2][4 pairs][512] bf16x2-words (8192 ushorts),
//           dwS [2][512] bf16 singles for tap 8 (1024 ushorts)
#define CW_TOTAL 474624
__global__ __launch_bounds__(256) void convw_all(
    const float* __restrict__ qkv_w, const float* __restrict__ off_w,
    const float* __restrict__ proj_w, const float* __restrict__ pi_w,
    const float* __restrict__ po_w,  const float* __restrict__ dw_w,
    ushort_t* __restrict__ ws)
{
    int idx = blockIdx.x * 256 + threadIdx.x;
    if (idx >= CW_TOTAL) return;
    int i = idx;
    if (i < 110592) { ws[idx] = f2bf(qkv_w[i]); return; }
    i -= 110592;
    if (i < 13824)  { ws[idx] = f2bf(off_w[i]); return; }
    i -= 13824;
    if (i < 36864)  { ws[idx] = f2bf(proj_w[i]); return; }
    i -= 36864;
    if (i < 196608) {
        int o = i / 192, k = i - o * 192;
        bool zero = (o == 510) || (o == 511) || (o >= 1022);
        int so = (o < 510) ? o : o - 2;
        ws[idx] = zero ? (ushort_t)0 : f2bf(pi_w[(size_t)so * 192 + k]);
        return;
    }
    i -= 196608;
    if (i < 98304) {
        int o = i >> 9, k = i & 511;
        ws[idx] = (k < HIDD) ? f2bf(po_w[(size_t)o * HIDD + k]) : (ushort_t)0;
        return;
    }
    i -= 98304;
    if (i < 9216) {   // dwT: [9][2][512] (edge path)
        int p = i >> 10, c = i & 1023;
        int half = c >> 9, cc = c & 511;
        ws[idx] = (cc < HIDD) ? f2bf(dw_w[(size_t)(half * HIDD + cc) * 9 + p]) : (ushort_t)0;
        return;
    }
    i -= 9216;
    if (i < 8192) {   // dwP: pair-packed; wi = i>>1, lo/hi = i&1
        int wi = i >> 1, hl = i & 1;
        int h = wi >> 11, rem = wi & 2047;
        int k = rem >> 9, c = rem & 511;
        int pos = 2 * k + hl;
        ws[idx] = (c < HIDD) ? f2bf(dw_w[(size_t)(h * HIDD + c) * 9 + pos]) : (ushort_t)0;
        return;
    }
    i -= 8192;
    {   // dwS: tap-8 singles [2][512]
        int h = i >> 9, c = i & 511;
        ws[idx] = (c < HIDD) ? f2bf(dw_w[(size_t)(h * HIDD + c) * 9 + 8]) : (ushort_t)0;
    }
}

// ---------------- MFMA GEMM: acc[o,n] = sum_k Wb[o,k]*X_pm[n,k] ------------
// XMODE 0: X pixel-major [N][KT] bf16.
// XMODE 1: X = 4 planes [4][N][48] (KT=192), attn plane-major output.
// XMODE 2: fused BiasFree-LN1 staging from f32 channel-major x (in R, stride
//          xzs, weights in W2). NSPLIT = BDIM/NTILE channel-splits.
// MODE 0: bf16 out at ((o/48)*NN+n)*48 + o%48      (qkv planes)
// MODE 2: f32  out at o*NN+n, += R                 (po epilogue)
// MODE 3: bf16 out at n*1024 + o (pi -> t), OPERAND-SWAPPED MFMA:
//         D[row=n][col=o] so o = lane&15 (lane dir) -> 16-lane 32B-contiguous
//         scalar stores, no cross-lane exchange.
// MODE 4: f32  out at o*NN+n, += R; fused LN -> bf16 XN2[n][192] (192 thr)
// MODE 5: merged qkv+off: obase<576 -> MODE0 to Yv; >=576 -> offsets to XN2
template<int MODE, int XMODE, int KT, int KP, int NTILE, int BDIM = 256>
__global__ __launch_bounds__(BDIM) void gemm_mfma(
    const ushort_t* __restrict__ Wb,
    const ushort_t* __restrict__ X,
    const float* __restrict__ R,
    void* __restrict__ Yv,
    int O,
    size_t xzs, size_t yzs, size_t rzs,
    const float* __restrict__ W2, ushort_t* __restrict__ XN2)
{
    extern __shared__ ushort_t Xt[];   // [NTILE][KP]
    constexpr int NSEG = KT >> 3;
    constexpr int NFR  = NTILE / 16;
    int tid = threadIdx.x;
    constexpr int nt = BDIM;
    constexpr int nw = BDIM >> 6;
    int z   = blockIdx.z;
    int n0  = blockIdx.x * NTILE;

    if constexpr (XMODE == 0 || XMODE == 1) {
        const ushort_t* Xb = X + (size_t)z * xzs;
        for (int u = tid; u < NTILE * NSEG; u += nt) {
            int r = u / NSEG, seg = u - r * NSEG;
            const ushort_t* src;
            if (XMODE == 0) {
                src = Xb + (size_t)(n0 + r) * KT + seg * 8;
            } else {
                int plane = seg / 6, w8 = seg - plane * 6;
                src = Xb + ((size_t)plane * NN + n0 + r) * 48 + w8 * 8;
            }
            *(uint4*)&Xt[(size_t)r * KP + seg * 8] = *(const uint4*)src;
        }
    } else {
        // XMODE 2: fused LN1. BDIM = NSPLIT * NTILE threads.
        constexpr int NSPLIT = BDIM / NTILE;
        constexpr int CPS    = CDIM / NSPLIT;
        __shared__ float lnr[NSPLIT][NTILE][2];
        int px = tid % NTILE, cs = tid / NTILE;
        const float* xp = R + (size_t)z * xzs + (size_t)(cs * CPS) * NN + n0 + px;
        float s = 0.f, s2 = 0.f;
        for (int cc = 0; cc < CPS; ++cc) {
            float v = xp[(size_t)cc * NN];
            s += v; s2 += v * v;
        }
        lnr[cs][px][0] = s; lnr[cs][px][1] = s2;
        __syncthreads();
        float ts = 0.f, ts2 = 0.f;
        #pragma unroll
        for (int q = 0; q < NSPLIT; ++q) { ts += lnr[q][px][0]; ts2 += lnr[q][px][1]; }
        float mu  = ts * (1.f / 192.f);
        float rs_ = rsqrtf(ts2 * (1.f / 192.f) - mu * mu + 1e-5f);
        for (int cc = 0; cc < CPS; cc += 2) {
            float v0 = xp[(size_t)cc * NN]       * rs_ * W2[cs * CPS + cc];
            float v1 = xp[(size_t)(cc + 1) * NN] * rs_ * W2[cs * CPS + cc + 1];
            unsigned int pk = (unsigned int)f2bf(v0) | ((unsigned int)f2bf(v1) << 16);
            *(unsigned int*)&Xt[(size_t)px * KP + cs * CPS + cc] = pk;
        }
    }
    __syncthreads();

    int w = tid >> 6, l = tid & 63;
    int o0w = blockIdx.y * (nw * 64) + w * 64;
    if (o0w >= O) return;

    int lrow = l & 15;
    int lk   = (l >> 4) * 8;

    f32x4 acc[4][NFR] = {};

    #pragma unroll
    for (int kk0 = 0; kk0 < KT; kk0 += 32) {
        short8 bfr[NFR];
        #pragma unroll
        for (int ni = 0; ni < NFR; ++ni)
            bfr[ni] = *(const short8*)&Xt[(size_t)(ni * 16 + lrow) * KP + kk0 + lk];
        short8 afr[4];
        #pragma unroll
        for (int mi = 0; mi < 4; ++mi) {
            int orow = o0w + mi * 16 + lrow;
            if (orow < O)
                afr[mi] = *(const short8*)(Wb + (size_t)orow * KT + kk0 + lk);
            else
                afr[mi] = short8{0,0,0,0,0,0,0,0};
        }
        #pragma unroll
        for (int mi = 0; mi < 4; ++mi)
            #pragma unroll
            for (int ni = 0; ni < NFR; ++ni) {
                if constexpr (MODE == 3)
                    // operand-swapped: D[row=n][col=o] (same dot products)
                    acc[mi][ni] = __builtin_amdgcn_mfma_f32_16x16x32_bf16(
                        bfr[ni], afr[mi], acc[mi][ni], 0, 0, 0);
                else
                    acc[mi][ni] = __builtin_amdgcn_mfma_f32_16x16x32_bf16(
                        afr[mi], bfr[ni], acc[mi][ni], 0, 0, 0);
            }
    }

    int orow0 = (l >> 4) * 4;

    if constexpr (MODE == 3) {
        // D' layout: col(lane&15) = o within tile, row((lane>>4)*4+r) = n.
        // Lanes 0..15 of each quad-group store 32B-contiguous o-runs per n-row.
        int ocol  = l & 15;
        int nrow0 = (l >> 4) * 4;
        ushort_t* dstB = (ushort_t*)Yv + (size_t)z * yzs;
        #pragma unroll
        for (int mi = 0; mi < 4; ++mi) {
            int o = o0w + mi * 16 + ocol;
            #pragma unroll
            for (int ni = 0; ni < NFR; ++ni) {
                int nb = n0 + ni * 16 + nrow0;
                #pragma unroll
                for (int r = 0; r < 4; ++r)
                    dstB[(size_t)(nb + r) * 1024 + o] = f2bf(acc[mi][ni][r]);
            }
        }
    } else if constexpr (MODE == 4) {
        __shared__ float red[3][NTILE][2];
        float s[NFR] = {}, s2[NFR] = {};
        #pragma unroll
        for (int mi = 0; mi < 4; ++mi)
            #pragma unroll
            for (int ni = 0; ni < NFR; ++ni) {
                int n = n0 + ni * 16 + lrow;
                int obase = o0w + mi * 16 + orow0;
                #pragma unroll
                for (int r = 0; r < 4; ++r) {
                    float v = acc[mi][ni][r] +
                              R[(size_t)z * rzs + (size_t)(obase + r) * NN + n];
                    acc[mi][ni][r] = v;
                    s[ni] += v; s2[ni] += v * v;
                }
            }
        #pragma unroll
        for (int ni = 0; ni < NFR; ++ni) {
            s[ni]  += __shfl_xor(s[ni], 16);  s[ni]  += __shfl_xor(s[ni], 32);
            s2[ni] += __shfl_xor(s2[ni], 16); s2[ni] += __shfl_xor(s2[ni], 32);
        }
        if (l < 16) {
            #pragma unroll
            for (int ni = 0; ni < NFR; ++ni) {
                red[w][ni * 16 + l][0] = s[ni];
                red[w][ni * 16 + l][1] = s2[ni];
            }
        }
        __syncthreads();
        float rsv[NFR];
        #pragma unroll
        for (int ni = 0; ni < NFR; ++ni) {
            int nl = ni * 16 + lrow;
            float ts  = red[0][nl][0] + red[1][nl][0] + red[2][nl][0];
            float ts2 = red[0][nl][1] + red[1][nl][1] + red[2][nl][1];
            float mu  = ts * (1.f / 192.f);
            float var = ts2 * (1.f / 192.f) - mu * mu;
            rsv[ni] = rsqrtf(var + 1e-5f);
        }
        #pragma unroll
        for (int mi = 0; mi < 4; ++mi)
            #pragma unroll
            for (int ni = 0; ni < NFR; ++ni) {
                int n = n0 + ni * 16 + lrow;
                int obase = o0w + mi * 16 + orow0;
                #pragma unroll
                for (int r = 0; r < 4; ++r)
                    ((float*)Yv)[(size_t)z * yzs + (size_t)(obase + r) * NN + n]
                        = acc[mi][ni][r];
                float rs_ = rsv[ni];
                unsigned int lo =
                    (unsigned int)f2bf(acc[mi][ni][0] * rs_ * W2[obase])
                  | ((unsigned int)f2bf(acc[mi][ni][1] * rs_ * W2[obase + 1]) << 16);
                unsigned int hi =
                    (unsigned int)f2bf(acc[mi][ni][2] * rs_ * W2[obase + 2])
                  | ((unsigned int)f2bf(acc[mi][ni][3] * rs_ * W2[obase + 3]) << 16);
                *(uint2*)(XN2 + (size_t)z * ((size_t)NN * CDIM)
                          + (size_t)n * CDIM + obase) = make_uint2(lo, hi);
            }
    } else {
        #pragma unroll
        for (int mi = 0; mi < 4; ++mi) {
            #pragma unroll
            for (int ni = 0; ni < NFR; ++ni) {
                int n = n0 + ni * 16 + lrow;
                int obase = o0w + mi * 16 + orow0;
                float v0 = acc[mi][ni][0], v1 = acc[mi][ni][1];
                float v2 = acc[mi][ni][2], v3 = acc[mi][ni][3];
                if (MODE == 0) {
                    if (obase >= O) continue;
                    unsigned int lo = (unsigned int)f2bf(v0) | ((unsigned int)f2bf(v1) << 16);
                    unsigned int hi = (unsigned int)f2bf(v2) | ((unsigned int)f2bf(v3) << 16);
                    size_t base = ((size_t)(obase / 48) * NN + n) * 48 + (obase % 48);
                    *(uint2*)((ushort_t*)Yv + (size_t)z * yzs + base) = make_uint2(lo, hi);
                } else if (MODE == 5) {
                    if (obase < 576) {
                        unsigned int lo = (unsigned int)f2bf(v0) | ((unsigned int)f2bf(v1) << 16);
                        unsigned int hi = (unsigned int)f2bf(v2) | ((unsigned int)f2bf(v3) << 16);
                        size_t base = ((size_t)(obase / 48) * NN + n) * 48 + (obase % 48);
                        *(uint2*)((ushort_t*)Yv + (size_t)z * yzs + base) = make_uint2(lo, hi);
                    } else {
                        float vv[4] = {v0, v1, v2, v3};
                        #pragma unroll
                        for (int r = 0; r < 4; ++r) {
                            int o = obase + r - 576;
                            if (o >= 0 && o < 72)
                                XN2[(size_t)z * rzs +
                                    ((size_t)(o / 18) * NN + n) * 24 + (o % 18)] = f2bf(vv[r]);
                        }
                    }
                } else {  // MODE 2
                    float vv[4] = {v0, v1, v2, v3};
                    #pragma unroll
                    for (int r = 0; r < 4; ++r) {
                        int o = obase + r;
                        if (o < O) {
                            size_t idx = (size_t)o * NN + n;
                            ((float*)Yv)[(size_t)z * yzs + idx] = vv[r] + R[(size_t)z * rzs + idx];
                        }
                    }
                }
            }
        }
    }
}

// ------------- deformable attention, single dispatch, XCD-bijective --------
__global__ __launch_bounds__(256, 2) void attn_kernel(
    const ushort_t* __restrict__ qkv_pm,   // [B][12][N][48]
    const ushort_t* __restrict__ off_pm,   // [B][4][N][24]
    const float* __restrict__ rpb,         // [4,9]
    ushort_t* __restrict__ out_pl)         // [B][4][N][48]
{
    int bid = blockIdx.x;                       // 0..2047
    int lin = (bid & 7) * 256 + (bid >> 3);
    int c   = lin >> 7;                         // 0..15
    int b   = c >> 3;
    int h   = (c >> 1) & 3;
    int half= c & 1;
    int r   = lin & 127;
    int py  = half * 64 + (r >> 1);
    int tid = threadIdx.x;
    int px  = (r & 1) * 64 + (tid >> 2);
    int s   = tid & 3;
    int n   = py * WW + px;

    const ushort_t* qkvB = qkv_pm + (size_t)b * 12 * NN * 48;
    const ushort_t* offB = off_pm + (size_t)b * 4 * NN * 24;
    ushort_t*       outB = out_pl + (size_t)b * 4 * NN * 48;

    union { uint4 u[3]; ushort_t v[24]; } ob;
    {
        const ushort_t* op = offB + ((size_t)h * NN + n) * 24;
        ob.u[0] = *(const uint4*)op;
        ob.u[1] = *(const uint4*)(op + 8);
        ob.u[2] = *(const uint4*)(op + 16);
    }

    int   baseu[9], dxu[9], dyu[9];
    float wyA[9], wxA[9];
    #pragma unroll
    for (int kpt = 0; kpt < 9; ++kpt) {
        float oy = bf2f(ob.v[kpt * 2 + 0]);
        float ox = bf2f(ob.v[kpt * 2 + 1]);
        float cy = fminf(fmaxf((float)(py + (kpt / 3) - 1) + oy, 0.f), 127.f);
        float cx = fminf(fmaxf((float)(px + (kpt % 3) - 1) + ox, 0.f), 127.f);
        float y0f = floorf(cy), x0f = floorf(cx);
        wyA[kpt] = cy - y0f; wxA[kpt] = cx - x0f;
        int y0 = (int)y0f, x0 = (int)x0f;
        baseu[kpt] = (y0 * WW + x0) * 48;
        dxu[kpt]   = (x0 < 127) ? 48 : 0;
        dyu[kpt]   = (y0 < 127) ? (WW * 48) : 0;
    }

    const ushort_t* qrow  = qkvB + ((size_t)h * NN + n) * 48;
    const ushort_t* kbase = qkvB + ((size_t)(4 + h) * NN) * 48;
    const ushort_t* vbase = qkvB + ((size_t)(8 + h) * NN) * 48;
    int co0 = s * 12;

    unsigned int qp[6];
    {
        uint2 a = *(const uint2*)(qrow + co0);
        uint2 bq = *(const uint2*)(qrow + co0 + 4);
        uint2 cq = *(const uint2*)(qrow + co0 + 8);
        qp[0] = a.x; qp[1] = a.y; qp[2] = bq.x; qp[3] = bq.y; qp[4] = cq.x; qp[5] = cq.y;
    }

    float logits[9];
    #pragma unroll
    for (int kpt = 0; kpt < 9; ++kpt) {
        const ushort_t* kb = kbase + baseu[kpt] + co0;
        int du = dxu[kpt], dv = dyu[kpt];
        float d0 = 0.f, d1 = 0.f, d2 = 0.f, d3 = 0.f;
        #pragma unroll
        for (int ch = 0; ch < 3; ++ch) {
            const ushort_t* p = kb + ch * 4;
            uint2 k0 = *(const uint2*)p;
            uint2 k1 = *(const uint2*)(p + du);
            uint2 k2 = *(const uint2*)(p + dv);
            uint2 k3 = *(const uint2*)(p + dv + du);
            d0 = dot2bf(k0.x, qp[2 * ch], d0); d0 = dot2bf(k0.y, qp[2 * ch + 1], d0);
            d1 = dot2bf(k1.x, qp[2 * ch], d1); d1 = dot2bf(k1.y, qp[2 * ch + 1], d1);
            d2 = dot2bf(k2.x, qp[2 * ch], d2); d2 = dot2bf(k2.y, qp[2 * ch + 1], d2);
            d3 = dot2bf(k3.x, qp[2 * ch], d3); d3 = dot2bf(k3.y, qp[2 * ch + 1], d3);
        }
        float wy = wyA[kpt], wx = wxA[kpt];
        float iy = 1.f - wy, ix = 1.f - wx;
        logits[kpt] = fmaf(wy * wx, d3, fmaf(wy * ix, d2,
                      fmaf(iy * wx, d1, iy * ix * d0)));
    }

    #pragma unroll
    for (int kpt = 0; kpt < 9; ++kpt) {
        float v = logits[kpt];
        v += __shfl_xor(v, 1);
        v += __shfl_xor(v, 2);
        logits[kpt] = v * 0.14433756729740643f + rpb[h * 9 + kpt];
    }
    float m = logits[0];
    #pragma unroll
    for (int i = 1; i < 9; ++i) m = fmaxf(m, logits[i]);
    float ssum = 0.f;
    #pragma unroll
    for (int i = 0; i < 9; ++i) { logits[i] = __expf(logits[i] - m); ssum += logits[i]; }
    float inv = 1.f / ssum;

    float oacc[12] = {};
    #pragma unroll
    for (int kpt = 0; kpt < 9; ++kpt) {
        float wy = wyA[kpt], wx = wxA[kpt];
        float iy = 1.f - wy, ix = 1.f - wx;
        float a = logits[kpt] * inv;
        unsigned int w01 = cvtpk(a * iy * ix, a * iy * wx);
        unsigned int w23 = cvtpk(a * wy * ix, a * wy * wx);
        const ushort_t* vb = vbase + baseu[kpt] + co0;
        int du = dxu[kpt], dv = dyu[kpt];
        #pragma unroll
        for (int ch = 0; ch < 3; ++ch) {
            const ushort_t* p = vb + ch * 4;
            uint2 A = *(const uint2*)p;
            uint2 Bv = *(const uint2*)(p + du);
            uint2 Cv = *(const uint2*)(p + dv);
            uint2 Dv = *(const uint2*)(p + dv + du);
            unsigned int T0 = __builtin_amdgcn_perm(A.x, Bv.x, 0x01000504u);
            unsigned int T1 = __builtin_amdgcn_perm(A.x, Bv.x, 0x03020706u);
            unsigned int U0 = __builtin_amdgcn_perm(Cv.x, Dv.x, 0x01000504u);
            unsigned int U1 = __builtin_amdgcn_perm(Cv.x, Dv.x, 0x03020706u);
            oacc[ch * 4 + 0] = dot2bf(U0, w23, dot2bf(T0, w01, oacc[ch * 4 + 0]));
            oacc[ch * 4 + 1] = dot2bf(U1, w23, dot2bf(T1, w01, oacc[ch * 4 + 1]));
            T0 = __builtin_amdgcn_perm(A.y, Bv.y, 0x01000504u);
            T1 = __builtin_amdgcn_perm(A.y, Bv.y, 0x03020706u);
            U0 = __builtin_amdgcn_perm(Cv.y, Dv.y, 0x01000504u);
            U1 = __builtin_amdgcn_perm(Cv.y, Dv.y, 0x03020706u);
            oacc[ch * 4 + 2] = dot2bf(U0, w23, dot2bf(T0, w01, oacc[ch * 4 + 2]));
            oacc[ch * 4 + 3] = dot2bf(U1, w23, dot2bf(T1, w01, oacc[ch * 4 + 3]));
        }
    }

    ushort_t* orow = outB + ((size_t)h * NN + n) * 48 + co0;
    #pragma unroll
    for (int ch = 0; ch < 3; ++ch) {
        unsigned int lo = (unsigned int)f2bf(oacc[ch * 4 + 0])
                        | ((unsigned int)f2bf(oacc[ch * 4 + 1]) << 16);
        unsigned int hi = (unsigned int)f2bf(oacc[ch * 4 + 2])
                        | ((unsigned int)f2bf(oacc[ch * 4 + 3]) << 16);
        *(uint2*)(orow + ch * 4) = make_uint2(lo, hi);
    }
}

// ------- depthwise 3x3 (both halves) + exact-GELU gate; 8 ch / thread ------
// Wave = one pixel -> interior/edge branch is wave-uniform.
// Interior: 4 tap-pairs via v_perm + prepacked bf16x2 weights + dot2.
__global__ __launch_bounds__(256) void dwgate_kernel(
    const ushort_t* __restrict__ t_pm,
    const ushort_t* __restrict__ wT,    // [9][2][512] (edge path)
    const unsigned int* __restrict__ wP,// [2][4][512] packed pairs
    const ushort_t* __restrict__ wS,    // [2][512] tap-8 singles
    ushort_t* __restrict__ g_pm)
{
    int b = blockIdx.y;
    const ushort_t* tB = t_pm + (size_t)b * NN * 1024;
    ushort_t*       gB = g_pm + (size_t)b * NN * 512;
    int bid = blockIdx.x;                        // 4096
    int lin = (bid & 7) * 512 + (bid >> 3);      // XCD-contiguous
    int idx = lin * 256 + threadIdx.x;           // over N*64
    int c0 = (idx & 63) * 8;
    int n  = idx >> 6;
    int y = n >> 7, x = n & 127;
    float a1[8] = {}, a2[8] = {};

    if (x >= 1 && x <= 126 && y >= 1 && y <= 126) {
        // ---- interior fast path: 4 pairs + 1 single per half ----
        const ushort_t* trow[9];
        #pragma unroll
        for (int p = 0; p < 9; ++p)
            trow[p] = tB + (size_t)((y + p / 3 - 1) * WW + (x + p % 3 - 1)) * 1024;
        #pragma unroll
        for (int hlf = 0; hlf < 2; ++hlf) {
            float* aa = hlf ? a2 : a1;
            int cb = c0 + hlf * 512;
            #pragma unroll
            for (int k = 0; k < 4; ++k) {
                uint4 A = *(const uint4*)(trow[2 * k] + cb);
                uint4 Bv = *(const uint4*)(trow[2 * k + 1] + cb);
                uint4 W0 = *(const uint4*)(wP + (size_t)(hlf * 4 + k) * 512 + c0);
                uint4 W1 = *(const uint4*)(wP + (size_t)(hlf * 4 + k) * 512 + c0 + 4);
                unsigned int Av[4] = {A.x, A.y, A.z, A.w};
                unsigned int Bw[4] = {Bv.x, Bv.y, Bv.z, Bv.w};
                unsigned int Wv[8] = {W0.x, W0.y, W0.z, W0.w, W1.x, W1.y, W1.z, W1.w};
                #pragma unroll
                for (int d = 0; d < 4; ++d) {
                    unsigned int T0 = __builtin_amdgcn_perm(Av[d], Bw[d], 0x01000504u);
                    unsigned int T1 = __builtin_amdgcn_perm(Av[d], Bw[d], 0x03020706u);
                    aa[2 * d]     = dot2bf(T0, Wv[2 * d],     aa[2 * d]);
                    aa[2 * d + 1] = dot2bf(T1, Wv[2 * d + 1], aa[2 * d + 1]);
                }
            }
            {   // single tap 8 (dy=+1, dx=+1)
                short8 tv = *(const short8*)(trow[8] + cb);
                short8 wv = *(const short8*)(wS + hlf * 512 + c0);
                #pragma unroll
                for (int j = 0; j < 8; ++j)
                    aa[j] = fmaf(bf2f((ushort_t)tv[j]), bf2f((ushort_t)wv[j]), aa[j]);
            }
        }
    } else {
        // ---- edge path: original scalar taps with bounds checks ----
        #pragma unroll
        for (int dy = 0; dy < 3; ++dy) {
            int yy = y + dy - 1;
            if (yy < 0 || yy > 127) continue;
            #pragma unroll
            for (int dx = 0; dx < 3; ++dx) {
                int xx = x + dx - 1;
                if (xx < 0 || xx > 127) continue;
                int p = dy * 3 + dx;
                const ushort_t* tr = tB + (size_t)(yy * WW + xx) * 1024;
                short8 t1 = *(const short8*)(tr + c0);
                short8 t2 = *(const short8*)(tr + 512 + c0);
                short8 w1 = *(const short8*)(wT + p * 1024 + c0);
                short8 w2 = *(const short8*)(wT + p * 1024 + 512 + c0);
                #pragma unroll
                for (int j = 0; j < 8; ++j) {
                    a1[j] = fmaf(bf2f((ushort_t)t1[j]), bf2f((ushort_t)w1[j]), a1[j]);
                    a2[j] = fmaf(bf2f((ushort_t)t2[j]), bf2f((ushort_t)w2[j]), a2[j]);
                }
            }
        }
    }
    short8 o8;
    #pragma unroll
    for (int j = 0; j < 8; ++j) {
        float ge = 0.5f * a1[j] * (1.f + erff(a1[j] * 0.70710678118654752f));
        o8[j] = (short)f2bf(ge * a2[j]);
    }
    *(short8*)(gB + (size_t)n * 512 + c0) = o8;
}

extern "C" void kernel_launch(void* const* d_in, const int* in_sizes, int n_in,
                              void* d_out, int out_size, void* d_ws, size_t ws_size,
                              hipStream_t stream)
{
    const float* x      = (const float*)d_in[0];
    const float* ln1_w  = (const float*)d_in[1];
    const float* ln2_w  = (const float*)d_in[2];
    const float* qkv_w  = (const float*)d_in[3];
    const float* off_w  = (const float*)d_in[4];
    const float* rpb    = (const float*)d_in[5];
    const float* proj_w = (const float*)d_in[6];
    const float* pi_w   = (const float*)d_in[7];
    const float* dw_w   = (const float*)d_in[8];
    const float* po_w   = (const float*)d_in[9];
    float* out = (float*)d_out;

    // ---- workspace layout (ushort units), ~137 MB ----
    ushort_t* ws = (ushort_t*)d_ws;
    ushort_t* qkv_wb  = ws;                                   // 648*192 merged
    ushort_t* proj_wb = qkv_wb  + 648 * 192;
    ushort_t* pi_wb   = proj_wb + 192 * 192;
    ushort_t* po_wb   = pi_wb   + 1024 * 192;
    ushort_t* dwT     = po_wb   + 192 * 512;                  // 9*1024
    ushort_t* dwP     = dwT     + 9 * 1024;                   // 8192 (pair words)
    ushort_t* dwS     = dwP     + 8192;                       // 1024
    ushort_t* xn      = dwS     + 1024;                       // attn-out [2][4][N][48]
    ushort_t* qkvb    = xn      + (size_t)2 * NN * CDIM;      // [2][12][N][48] (also g)
    ushort_t* offb    = qkvb    + (size_t)2 * 12 * NN * 48;   // [2][4][N][24]
    ushort_t* t       = offb    + (size_t)2 * 4 * NN * 24;    // [2][N][1024]
    ushort_t* xn2     = t       + (size_t)2 * NN * 1024;      // [2][N][192]
    ushort_t* attn    = xn;
    ushort_t* g       = qkvb;

    dim3 blk(256);

    convw_all<<<dim3((CW_TOTAL + 255) / 256), blk, 0, stream>>>(
        qkv_w, off_w, proj_w, pi_w, po_w, dw_w, ws);

    const int shm64  = 64 * 200 * 2;        // 25600 B
    const int shm128 = 128 * 200 * 2;       // 51200 B
    const int shm512 = 64 * 520 * 2;        // 66560 B
    const size_t XN_S   = (size_t)NN * CDIM;
    const size_t QKV_S  = (size_t)12 * NN * 48;
    const size_t OFF_S  = (size_t)4 * NN * 24;
    const size_t APL_S  = (size_t)4 * NN * 48;
    const size_t T_S    = (size_t)NN * 1024;
    const size_t G_S    = (size_t)NN * 512;
    const size_t CM_S   = (size_t)CDIM * NN;

    // 1. qkv planes + offsets + FUSED LN1: 768-thread blocks
    gemm_mfma<5, 2, 192, 200, 64, 768><<<dim3(256, 1, 2), dim3(768), shm64, stream>>>(
        qkv_wb, nullptr, x, qkvb, 648, CM_S, QKV_S, OFF_S, ln1_w, offb);
    // 2. deformable attention
    attn_kernel<<<dim3(2048), blk, 0, stream>>>(qkvb, offb, rpb, attn);
    // 3. x1 = x + proj_wb @ attn -> d_out, fused LN2 -> xn2
    gemm_mfma<4, 1, 192, 200, 128, 192><<<dim3(128, 1, 2), dim3(192), shm128, stream>>>(
        proj_wb, attn, x, out, 192, APL_S, CM_S, CM_S, ln2_w, xn2);
    // 4. t = pi_wb @ xn2   (operand-swapped MFMA -> lane-direction o stores)
    gemm_mfma<3, 0, 192, 200, 128, 512><<<dim3(128, 2, 2), dim3(512), shm128, stream>>>(
        pi_wb, xn2, nullptr, t, 1024, XN_S, T_S, 0, nullptr, nullptr);
    // 5. g = gelu(dw(t1)) * dw(t2)  (pair-packed interior path)
    dwgate_kernel<<<dim3(NN * 64 / 256, 2), blk, 0, stream>>>(
        t, dwT, (const unsigned int*)dwP, dwS, g);
    // 6. out = x1 + po_wb @ g
    gemm_mfma<2, 0, 512, 520, 64, 192><<<dim3(256, 1, 2), dim3(192), shm512, stream>>>(
        po_wb, g, out, out, 192, G_S, CM_S, CM_S, nullptr, nullptr);
}

// Round 24
// 216.461 us; speedup vs baseline: 1.0545x; 1.0420x over previous
//
#include <hip/hip_runtime.h>
#include <math.h>

#define NN 16384      // H*W per image
#define WW 128
#define CDIM 192
#define HIDD 510
#define BB 2

typedef unsigned short ushort_t;
using short8 = __attribute__((ext_vector_type(8))) short;
using f32x4  = __attribute__((ext_vector_type(4))) float;

__device__ __forceinline__ float bf2f(ushort_t u) {
    union { unsigned int i; float f; } v; v.i = ((unsigned int)u) << 16; return v.f;
}
__device__ __forceinline__ ushort_t f2bf(float f) {
    union { unsigned int i; float f; } v; v.f = f;
    unsigned int i = v.i;
    return (ushort_t)((i + 0x7fffu + ((i >> 16) & 1u)) >> 16);  // RNE
}
// d = a.bf16[0]*b.bf16[0] + a.bf16[1]*b.bf16[1] + c   (V_DOT2_F32_BF16)
__device__ __forceinline__ float dot2bf(unsigned int a, unsigned int b, float c) {
    float d;
    asm("v_dot2_f32_bf16 %0, %1, %2, %3" : "=v"(d) : "v"(a), "v"(b), "v"(c));
    return d;
}
// pack two f32 -> bf16x2 word (lo = a, hi = b)
__device__ __forceinline__ unsigned int cvtpk(float a, float b) {
    unsigned int r;
    asm("v_cvt_pk_bf16_f32 %0, %1, %2" : "=v"(r) : "v"(a), "v"(b));
    return r;
}

// -------- ALL weight conversions in one kernel (range-dispatched) ----------
// appended: dwP [2][4 pairs][512] bf16x2-words (8192 ushorts),
//           dwS [2][512] bf16 singles for tap 8 (1024 ushorts)
#define CW_TOTAL 474624
__global__ __launch_bounds__(256) void convw_all(
    const float* __restrict__ qkv_w, const float* __restrict__ off_w,
    const float* __restrict__ proj_w, const float* __restrict__ pi_w,
    const float* __restrict__ po_w,  const float* __restrict__ dw_w,
    ushort_t* __restrict__ ws)
{
    int idx = blockIdx.x * 256 + threadIdx.x;
    if (idx >= CW_TOTAL) return;
    int i = idx;
    if (i < 110592) { ws[idx] = f2bf(qkv_w[i]); return; }
    i -= 110592;
    if (i < 13824)  { ws[idx] = f2bf(off_w[i]); return; }
    i -= 13824;
    if (i < 36864)  { ws[idx] = f2bf(proj_w[i]); return; }
    i -= 36864;
    if (i < 196608) {
        int o = i / 192, k = i - o * 192;
        bool zero = (o == 510) || (o == 511) || (o >= 1022);
        int so = (o < 510) ? o : o - 2;
        ws[idx] = zero ? (ushort_t)0 : f2bf(pi_w[(size_t)so * 192 + k]);
        return;
    }
    i -= 196608;
    if (i < 98304) {
        int o = i >> 9, k = i & 511;
        ws[idx] = (k < HIDD) ? f2bf(po_w[(size_t)o * HIDD + k]) : (ushort_t)0;
        return;
    }
    i -= 98304;
    if (i < 9216) {   // dwT: [9][2][512] (edge path)
        int p = i >> 10, c = i & 1023;
        int half = c >> 9, cc = c & 511;
        ws[idx] = (cc < HIDD) ? f2bf(dw_w[(size_t)(half * HIDD + cc) * 9 + p]) : (ushort_t)0;
        return;
    }
    i -= 9216;
    if (i < 8192) {   // dwP: pair-packed; wi = i>>1, lo/hi = i&1
        int wi = i >> 1, hl = i & 1;
        int h = wi >> 11, rem = wi & 2047;
        int k = rem >> 9, c = rem & 511;
        int pos = 2 * k + hl;
        ws[idx] = (c < HIDD) ? f2bf(dw_w[(size_t)(h * HIDD + c) * 9 + pos]) : (ushort_t)0;
        return;
    }
    i -= 8192;
    {   // dwS: tap-8 singles [2][512]
        int h = i >> 9, c = i & 511;
        ws[idx] = (c < HIDD) ? f2bf(dw_w[(size_t)(h * HIDD + c) * 9 + 8]) : (ushort_t)0;
    }
}

// ---------------- MFMA GEMM: acc[o,n] = sum_k Wb[o,k]*X_pm[n,k] ------------
// XMODE 0: X pixel-major [N][KT] bf16.
// XMODE 1: X = 4 planes [4][N][48] (KT=192), attn plane-major output.
// XMODE 2: fused BiasFree-LN1 staging from f32 channel-major x (in R, stride
//          xzs, weights in W2). NSPLIT = BDIM/NTILE channel-splits.
// MODE 0: bf16 out at ((o/48)*NN+n)*48 + o%48      (qkv planes)
// MODE 2: f32  out at o*NN+n, += R                 (po epilogue)
// MODE 3: bf16 out at n*1024 + o (pi -> t), OPERAND-SWAPPED MFMA:
//         D[row=n][col=o], o = lane&15 in the lane direction; store nest is
//         (ni,r) outer / mi inner so the 4 stores filling one n-row's 128B
//         span are temporally adjacent (L2 write-combine, full-line evict).
// MODE 4: f32  out at o*NN+n, += R; fused LN -> bf16 XN2[n][192] (192 thr)
// MODE 5: merged qkv+off: obase<576 -> MODE0 to Yv; >=576 -> offsets to XN2
template<int MODE, int XMODE, int KT, int KP, int NTILE, int BDIM = 256>
__global__ __launch_bounds__(BDIM) void gemm_mfma(
    const ushort_t* __restrict__ Wb,
    const ushort_t* __restrict__ X,
    const float* __restrict__ R,
    void* __restrict__ Yv,
    int O,
    size_t xzs, size_t yzs, size_t rzs,
    const float* __restrict__ W2, ushort_t* __restrict__ XN2)
{
    extern __shared__ ushort_t Xt[];   // [NTILE][KP]
    constexpr int NSEG = KT >> 3;
    constexpr int NFR  = NTILE / 16;
    int tid = threadIdx.x;
    constexpr int nt = BDIM;
    constexpr int nw = BDIM >> 6;
    int z   = blockIdx.z;
    int n0  = blockIdx.x * NTILE;

    if constexpr (XMODE == 0 || XMODE == 1) {
        const ushort_t* Xb = X + (size_t)z * xzs;
        for (int u = tid; u < NTILE * NSEG; u += nt) {
            int r = u / NSEG, seg = u - r * NSEG;
            const ushort_t* src;
            if (XMODE == 0) {
                src = Xb + (size_t)(n0 + r) * KT + seg * 8;
            } else {
                int plane = seg / 6, w8 = seg - plane * 6;
                src = Xb + ((size_t)plane * NN + n0 + r) * 48 + w8 * 8;
            }
            *(uint4*)&Xt[(size_t)r * KP + seg * 8] = *(const uint4*)src;
        }
    } else {
        // XMODE 2: fused LN1. BDIM = NSPLIT * NTILE threads.
        constexpr int NSPLIT = BDIM / NTILE;
        constexpr int CPS    = CDIM / NSPLIT;
        __shared__ float lnr[NSPLIT][NTILE][2];
        int px = tid % NTILE, cs = tid / NTILE;
        const float* xp = R + (size_t)z * xzs + (size_t)(cs * CPS) * NN + n0 + px;
        float s = 0.f, s2 = 0.f;
        for (int cc = 0; cc < CPS; ++cc) {
            float v = xp[(size_t)cc * NN];
            s += v; s2 += v * v;
        }
        lnr[cs][px][0] = s; lnr[cs][px][1] = s2;
        __syncthreads();
        float ts = 0.f, ts2 = 0.f;
        #pragma unroll
        for (int q = 0; q < NSPLIT; ++q) { ts += lnr[q][px][0]; ts2 += lnr[q][px][1]; }
        float mu  = ts * (1.f / 192.f);
        float rs_ = rsqrtf(ts2 * (1.f / 192.f) - mu * mu + 1e-5f);
        for (int cc = 0; cc < CPS; cc += 2) {
            float v0 = xp[(size_t)cc * NN]       * rs_ * W2[cs * CPS + cc];
            float v1 = xp[(size_t)(cc + 1) * NN] * rs_ * W2[cs * CPS + cc + 1];
            unsigned int pk = (unsigned int)f2bf(v0) | ((unsigned int)f2bf(v1) << 16);
            *(unsigned int*)&Xt[(size_t)px * KP + cs * CPS + cc] = pk;
        }
    }
    __syncthreads();

    int w = tid >> 6, l = tid & 63;
    int o0w = blockIdx.y * (nw * 64) + w * 64;
    if (o0w >= O) return;

    int lrow = l & 15;
    int lk   = (l >> 4) * 8;

    f32x4 acc[4][NFR] = {};

    #pragma unroll
    for (int kk0 = 0; kk0 < KT; kk0 += 32) {
        short8 bfr[NFR];
        #pragma unroll
        for (int ni = 0; ni < NFR; ++ni)
            bfr[ni] = *(const short8*)&Xt[(size_t)(ni * 16 + lrow) * KP + kk0 + lk];
        short8 afr[4];
        #pragma unroll
        for (int mi = 0; mi < 4; ++mi) {
            int orow = o0w + mi * 16 + lrow;
            if (orow < O)
                afr[mi] = *(const short8*)(Wb + (size_t)orow * KT + kk0 + lk);
            else
                afr[mi] = short8{0,0,0,0,0,0,0,0};
        }
        #pragma unroll
        for (int mi = 0; mi < 4; ++mi)
            #pragma unroll
            for (int ni = 0; ni < NFR; ++ni) {
                if constexpr (MODE == 3)
                    // operand-swapped: D[row=n][col=o] (same dot products)
                    acc[mi][ni] = __builtin_amdgcn_mfma_f32_16x16x32_bf16(
                        bfr[ni], afr[mi], acc[mi][ni], 0, 0, 0);
                else
                    acc[mi][ni] = __builtin_amdgcn_mfma_f32_16x16x32_bf16(
                        afr[mi], bfr[ni], acc[mi][ni], 0, 0, 0);
            }
    }

    int orow0 = (l >> 4) * 4;

    if constexpr (MODE == 3) {
        // D' layout: col(lane&15) = o within tile, row((lane>>4)*4+r) = n.
        // (ni,r) outer / mi inner: the 4 mi stores fill 128B of one n-row
        // back-to-back so L2 write-combines full lines.
        int ocol  = l & 15;
        int nrow0 = (l >> 4) * 4;
        ushort_t* dstB = (ushort_t*)Yv + (size_t)z * yzs;
        #pragma unroll
        for (int ni = 0; ni < NFR; ++ni) {
            int nb = n0 + ni * 16 + nrow0;
            #pragma unroll
            for (int r = 0; r < 4; ++r) {
                ushort_t* row = dstB + (size_t)(nb + r) * 1024;
                #pragma unroll
                for (int mi = 0; mi < 4; ++mi)
                    row[o0w + mi * 16 + ocol] = f2bf(acc[mi][ni][r]);
            }
        }
    } else if constexpr (MODE == 4) {
        __shared__ float red[3][NTILE][2];
        float s[NFR] = {}, s2[NFR] = {};
        #pragma unroll
        for (int mi = 0; mi < 4; ++mi)
            #pragma unroll
            for (int ni = 0; ni < NFR; ++ni) {
                int n = n0 + ni * 16 + lrow;
                int obase = o0w + mi * 16 + orow0;
                #pragma unroll
                for (int r = 0; r < 4; ++r) {
                    float v = acc[mi][ni][r] +
                              R[(size_t)z * rzs + (size_t)(obase + r) * NN + n];
                    acc[mi][ni][r] = v;
                    s[ni] += v; s2[ni] += v * v;
                }
            }
        #pragma unroll
        for (int ni = 0; ni < NFR; ++ni) {
            s[ni]  += __shfl_xor(s[ni], 16);  s[ni]  += __shfl_xor(s[ni], 32);
            s2[ni] += __shfl_xor(s2[ni], 16); s2[ni] += __shfl_xor(s2[ni], 32);
        }
        if (l < 16) {
            #pragma unroll
            for (int ni = 0; ni < NFR; ++ni) {
                red[w][ni * 16 + l][0] = s[ni];
                red[w][ni * 16 + l][1] = s2[ni];
            }
        }
        __syncthreads();
        float rsv[NFR];
        #pragma unroll
        for (int ni = 0; ni < NFR; ++ni) {
            int nl = ni * 16 + lrow;
            float ts  = red[0][nl][0] + red[1][nl][0] + red[2][nl][0];
            float ts2 = red[0][nl][1] + red[1][nl][1] + red[2][nl][1];
            float mu  = ts * (1.f / 192.f);
            float var = ts2 * (1.f / 192.f) - mu * mu;
            rsv[ni] = rsqrtf(var + 1e-5f);
        }
        #pragma unroll
        for (int mi = 0; mi < 4; ++mi)
            #pragma unroll
            for (int ni = 0; ni < NFR; ++ni) {
                int n = n0 + ni * 16 + lrow;
                int obase = o0w + mi * 16 + orow0;
                #pragma unroll
                for (int r = 0; r < 4; ++r)
                    ((float*)Yv)[(size_t)z * yzs + (size_t)(obase + r) * NN + n]
                        = acc[mi][ni][r];
                float rs_ = rsv[ni];
                unsigned int lo =
                    (unsigned int)f2bf(acc[mi][ni][0] * rs_ * W2[obase])
                  | ((unsigned int)f2bf(acc[mi][ni][1] * rs_ * W2[obase + 1]) << 16);
                unsigned int hi =
                    (unsigned int)f2bf(acc[mi][ni][2] * rs_ * W2[obase + 2])
                  | ((unsigned int)f2bf(acc[mi][ni][3] * rs_ * W2[obase + 3]) << 16);
                *(uint2*)(XN2 + (size_t)z * ((size_t)NN * CDIM)
                          + (size_t)n * CDIM + obase) = make_uint2(lo, hi);
            }
    } else {
        #pragma unroll
        for (int mi = 0; mi < 4; ++mi) {
            #pragma unroll
            for (int ni = 0; ni < NFR; ++ni) {
                int n = n0 + ni * 16 + lrow;
                int obase = o0w + mi * 16 + orow0;
                float v0 = acc[mi][ni][0], v1 = acc[mi][ni][1];
                float v2 = acc[mi][ni][2], v3 = acc[mi][ni][3];
                if (MODE == 0) {
                    if (obase >= O) continue;
                    unsigned int lo = (unsigned int)f2bf(v0) | ((unsigned int)f2bf(v1) << 16);
                    unsigned int hi = (unsigned int)f2bf(v2) | ((unsigned int)f2bf(v3) << 16);
                    size_t base = ((size_t)(obase / 48) * NN + n) * 48 + (obase % 48);
                    *(uint2*)((ushort_t*)Yv + (size_t)z * yzs + base) = make_uint2(lo, hi);
                } else if (MODE == 5) {
                    if (obase < 576) {
                        unsigned int lo = (unsigned int)f2bf(v0) | ((unsigned int)f2bf(v1) << 16);
                        unsigned int hi = (unsigned int)f2bf(v2) | ((unsigned int)f2bf(v3) << 16);
                        size_t base = ((size_t)(obase / 48) * NN + n) * 48 + (obase % 48);
                        *(uint2*)((ushort_t*)Yv + (size_t)z * yzs + base) = make_uint2(lo, hi);
                    } else {
                        float vv[4] = {v0, v1, v2, v3};
                        #pragma unroll
                        for (int r = 0; r < 4; ++r) {
                            int o = obase + r - 576;
                            if (o >= 0 && o < 72)
                                XN2[(size_t)z * rzs +
                                    ((size_t)(o / 18) * NN + n) * 24 + (o % 18)] = f2bf(vv[r]);
                        }
                    }
                } else {  // MODE 2
                    float vv[4] = {v0, v1, v2, v3};
                    #pragma unroll
                    for (int r = 0; r < 4; ++r) {
                        int o = obase + r;
                        if (o < O) {
                            size_t idx = (size_t)o * NN + n;
                            ((float*)Yv)[(size_t)z * yzs + idx] = vv[r] + R[(size_t)z * rzs + idx];
                        }
                    }
                }
            }
        }
    }
}

// ------------- deformable attention, single dispatch, XCD-bijective --------
__global__ __launch_bounds__(256, 2) void attn_kernel(
    const ushort_t* __restrict__ qkv_pm,   // [B][12][N][48]
    const ushort_t* __restrict__ off_pm,   // [B][4][N][24]
    const float* __restrict__ rpb,         // [4,9]
    ushort_t* __restrict__ out_pl)         // [B][4][N][48]
{
    int bid = blockIdx.x;                       // 0..2047
    int lin = (bid & 7) * 256 + (bid >> 3);
    int c   = lin >> 7;                         // 0..15
    int b   = c >> 3;
    int h   = (c >> 1) & 3;
    int half= c & 1;
    int r   = lin & 127;
    int py  = half * 64 + (r >> 1);
    int tid = threadIdx.x;
    int px  = (r & 1) * 64 + (tid >> 2);
    int s   = tid & 3;
    int n   = py * WW + px;

    const ushort_t* qkvB = qkv_pm + (size_t)b * 12 * NN * 48;
    const ushort_t* offB = off_pm + (size_t)b * 4 * NN * 24;
    ushort_t*       outB = out_pl + (size_t)b * 4 * NN * 48;

    union { uint4 u[3]; ushort_t v[24]; } ob;
    {
        const ushort_t* op = offB + ((size_t)h * NN + n) * 24;
        ob.u[0] = *(const uint4*)op;
        ob.u[1] = *(const uint4*)(op + 8);
        ob.u[2] = *(const uint4*)(op + 16);
    }

    int   baseu[9], dxu[9], dyu[9];
    float wyA[9], wxA[9];
    #pragma unroll
    for (int kpt = 0; kpt < 9; ++kpt) {
        float oy = bf2f(ob.v[kpt * 2 + 0]);
        float ox = bf2f(ob.v[kpt * 2 + 1]);
        float cy = fminf(fmaxf((float)(py + (kpt / 3) - 1) + oy, 0.f), 127.f);
        float cx = fminf(fmaxf((float)(px + (kpt % 3) - 1) + ox, 0.f), 127.f);
        float y0f = floorf(cy), x0f = floorf(cx);
        wyA[kpt] = cy - y0f; wxA[kpt] = cx - x0f;
        int y0 = (int)y0f, x0 = (int)x0f;
        baseu[kpt] = (y0 * WW + x0) * 48;
        dxu[kpt]   = (x0 < 127) ? 48 : 0;
        dyu[kpt]   = (y0 < 127) ? (WW * 48) : 0;
    }

    const ushort_t* qrow  = qkvB + ((size_t)h * NN + n) * 48;
    const ushort_t* kbase = qkvB + ((size_t)(4 + h) * NN) * 48;
    const ushort_t* vbase = qkvB + ((size_t)(8 + h) * NN) * 48;
    int co0 = s * 12;

    unsigned int qp[6];
    {
        uint2 a = *(const uint2*)(qrow + co0);
        uint2 bq = *(const uint2*)(qrow + co0 + 4);
        uint2 cq = *(const uint2*)(qrow + co0 + 8);
        qp[0] = a.x; qp[1] = a.y; qp[2] = bq.x; qp[3] = bq.y; qp[4] = cq.x; qp[5] = cq.y;
    }

    float logits[9];
    #pragma unroll
    for (int kpt = 0; kpt < 9; ++kpt) {
        const ushort_t* kb = kbase + baseu[kpt] + co0;
        int du = dxu[kpt], dv = dyu[kpt];
        float d0 = 0.f, d1 = 0.f, d2 = 0.f, d3 = 0.f;
        #pragma unroll
        for (int ch = 0; ch < 3; ++ch) {
            const ushort_t* p = kb + ch * 4;
            uint2 k0 = *(const uint2*)p;
            uint2 k1 = *(const uint2*)(p + du);
            uint2 k2 = *(const uint2*)(p + dv);
            uint2 k3 = *(const uint2*)(p + dv + du);
            d0 = dot2bf(k0.x, qp[2 * ch], d0); d0 = dot2bf(k0.y, qp[2 * ch + 1], d0);
            d1 = dot2bf(k1.x, qp[2 * ch], d1); d1 = dot2bf(k1.y, qp[2 * ch + 1], d1);
            d2 = dot2bf(k2.x, qp[2 * ch], d2); d2 = dot2bf(k2.y, qp[2 * ch + 1], d2);
            d3 = dot2bf(k3.x, qp[2 * ch], d3); d3 = dot2bf(k3.y, qp[2 * ch + 1], d3);
        }
        float wy = wyA[kpt], wx = wxA[kpt];
        float iy = 1.f - wy, ix = 1.f - wx;
        logits[kpt] = fmaf(wy * wx, d3, fmaf(wy * ix, d2,
                      fmaf(iy * wx, d1, iy * ix * d0)));
    }

    #pragma unroll
    for (int kpt = 0; kpt < 9; ++kpt) {
        float v = logits[kpt];
        v += __shfl_xor(v, 1);
        v += __shfl_xor(v, 2);
        logits[kpt] = v * 0.14433756729740643f + rpb[h * 9 + kpt];
    }
    float m = logits[0];
    #pragma unroll
    for (int i = 1; i < 9; ++i) m = fmaxf(m, logits[i]);
    float ssum = 0.f;
    #pragma unroll
    for (int i = 0; i < 9; ++i) { logits[i] = __expf(logits[i] - m); ssum += logits[i]; }
    float inv = 1.f / ssum;

    float oacc[12] = {};
    #pragma unroll
    for (int kpt = 0; kpt < 9; ++kpt) {
        float wy = wyA[kpt], wx = wxA[kpt];
        float iy = 1.f - wy, ix = 1.f - wx;
        float a = logits[kpt] * inv;
        unsigned int w01 = cvtpk(a * iy * ix, a * iy * wx);
        unsigned int w23 = cvtpk(a * wy * ix, a * wy * wx);
        const ushort_t* vb = vbase + baseu[kpt] + co0;
        int du = dxu[kpt], dv = dyu[kpt];
        #pragma unroll
        for (int ch = 0; ch < 3; ++ch) {
            const ushort_t* p = vb + ch * 4;
            uint2 A = *(const uint2*)p;
            uint2 Bv = *(const uint2*)(p + du);
            uint2 Cv = *(const uint2*)(p + dv);
            uint2 Dv = *(const uint2*)(p + dv + du);
            unsigned int T0 = __builtin_amdgcn_perm(A.x, Bv.x, 0x01000504u);
            unsigned int T1 = __builtin_amdgcn_perm(A.x, Bv.x, 0x03020706u);
            unsigned int U0 = __builtin_amdgcn_perm(Cv.x, Dv.x, 0x01000504u);
            unsigned int U1 = __builtin_amdgcn_perm(Cv.x, Dv.x, 0x03020706u);
            oacc[ch * 4 + 0] = dot2bf(U0, w23, dot2bf(T0, w01, oacc[ch * 4 + 0]));
            oacc[ch * 4 + 1] = dot2bf(U1, w23, dot2bf(T1, w01, oacc[ch * 4 + 1]));
            T0 = __builtin_amdgcn_perm(A.y, Bv.y, 0x01000504u);
            T1 = __builtin_amdgcn_perm(A.y, Bv.y, 0x03020706u);
            U0 = __builtin_amdgcn_perm(Cv.y, Dv.y, 0x01000504u);
            U1 = __builtin_amdgcn_perm(Cv.y, Dv.y, 0x03020706u);
            oacc[ch * 4 + 2] = dot2bf(U0, w23, dot2bf(T0, w01, oacc[ch * 4 + 2]));
            oacc[ch * 4 + 3] = dot2bf(U1, w23, dot2bf(T1, w01, oacc[ch * 4 + 3]));
        }
    }

    ushort_t* orow = outB + ((size_t)h * NN + n) * 48 + co0;
    #pragma unroll
    for (int ch = 0; ch < 3; ++ch) {
        unsigned int lo = (unsigned int)f2bf(oacc[ch * 4 + 0])
                        | ((unsigned int)f2bf(oacc[ch * 4 + 1]) << 16);
        unsigned int hi = (unsigned int)f2bf(oacc[ch * 4 + 2])
                        | ((unsigned int)f2bf(oacc[ch * 4 + 3]) << 16);
        *(uint2*)(orow + ch * 4) = make_uint2(lo, hi);
    }
}

// ------- depthwise 3x3 (both halves) + exact-GELU gate; 8 ch / thread ------
// Wave = one pixel -> interior/edge branch is wave-uniform.
// Interior: 4 tap-pairs via v_perm + prepacked bf16x2 weights + dot2.
__global__ __launch_bounds__(256) void dwgate_kernel(
    const ushort_t* __restrict__ t_pm,
    const ushort_t* __restrict__ wT,    // [9][2][512] (edge path)
    const unsigned int* __restrict__ wP,// [2][4][512] packed pairs
    const ushort_t* __restrict__ wS,    // [2][512] tap-8 singles
    ushort_t* __restrict__ g_pm)
{
    int b = blockIdx.y;
    const ushort_t* tB = t_pm + (size_t)b * NN * 1024;
    ushort_t*       gB = g_pm + (size_t)b * NN * 512;
    int bid = blockIdx.x;                        // 4096
    int lin = (bid & 7) * 512 + (bid >> 3);      // XCD-contiguous
    int idx = lin * 256 + threadIdx.x;           // over N*64
    int c0 = (idx & 63) * 8;
    int n  = idx >> 6;
    int y = n >> 7, x = n & 127;
    float a1[8] = {}, a2[8] = {};

    if (x >= 1 && x <= 126 && y >= 1 && y <= 126) {
        // ---- interior fast path: 4 pairs + 1 single per half ----
        const ushort_t* trow[9];
        #pragma unroll
        for (int p = 0; p < 9; ++p)
            trow[p] = tB + (size_t)((y + p / 3 - 1) * WW + (x + p % 3 - 1)) * 1024;
        #pragma unroll
        for (int hlf = 0; hlf < 2; ++hlf) {
            float* aa = hlf ? a2 : a1;
            int cb = c0 + hlf * 512;
            #pragma unroll
            for (int k = 0; k < 4; ++k) {
                uint4 A = *(const uint4*)(trow[2 * k] + cb);
                uint4 Bv = *(const uint4*)(trow[2 * k + 1] + cb);
                uint4 W0 = *(const uint4*)(wP + (size_t)(hlf * 4 + k) * 512 + c0);
                uint4 W1 = *(const uint4*)(wP + (size_t)(hlf * 4 + k) * 512 + c0 + 4);
                unsigned int Av[4] = {A.x, A.y, A.z, A.w};
                unsigned int Bw[4] = {Bv.x, Bv.y, Bv.z, Bv.w};
                unsigned int Wv[8] = {W0.x, W0.y, W0.z, W0.w, W1.x, W1.y, W1.z, W1.w};
                #pragma unroll
                for (int d = 0; d < 4; ++d) {
                    unsigned int T0 = __builtin_amdgcn_perm(Av[d], Bw[d], 0x01000504u);
                    unsigned int T1 = __builtin_amdgcn_perm(Av[d], Bw[d], 0x03020706u);
                    aa[2 * d]     = dot2bf(T0, Wv[2 * d],     aa[2 * d]);
                    aa[2 * d + 1] = dot2bf(T1, Wv[2 * d + 1], aa[2 * d + 1]);
                }
            }
            {   // single tap 8 (dy=+1, dx=+1)
                short8 tv = *(const short8*)(trow[8] + cb);
                short8 wv = *(const short8*)(wS + hlf * 512 + c0);
                #pragma unroll
                for (int j = 0; j < 8; ++j)
                    aa[j] = fmaf(bf2f((ushort_t)tv[j]), bf2f((ushort_t)wv[j]), aa[j]);
            }
        }
    } else {
        // ---- edge path: original scalar taps with bounds checks ----
        #pragma unroll
        for (int dy = 0; dy < 3; ++dy) {
            int yy = y + dy - 1;
            if (yy < 0 || yy > 127) continue;
            #pragma unroll
            for (int dx = 0; dx < 3; ++dx) {
                int xx = x + dx - 1;
                if (xx < 0 || xx > 127) continue;
                int p = dy * 3 + dx;
                const ushort_t* tr = tB + (size_t)(yy * WW + xx) * 1024;
                short8 t1 = *(const short8*)(tr + c0);
                short8 t2 = *(const short8*)(tr + 512 + c0);
                short8 w1 = *(const short8*)(wT + p * 1024 + c0);
                short8 w2 = *(const short8*)(wT + p * 1024 + 512 + c0);
                #pragma unroll
                for (int j = 0; j < 8; ++j) {
                    a1[j] = fmaf(bf2f((ushort_t)t1[j]), bf2f((ushort_t)w1[j]), a1[j]);
                    a2[j] = fmaf(bf2f((ushort_t)t2[j]), bf2f((ushort_t)w2[j]), a2[j]);
                }
            }
        }
    }
    short8 o8;
    #pragma unroll
    for (int j = 0; j < 8; ++j) {
        float ge = 0.5f * a1[j] * (1.f + erff(a1[j] * 0.70710678118654752f));
        o8[j] = (short)f2bf(ge * a2[j]);
    }
    *(short8*)(gB + (size_t)n * 512 + c0) = o8;
}

extern "C" void kernel_launch(void* const* d_in, const int* in_sizes, int n_in,
                              void* d_out, int out_size, void* d_ws, size_t ws_size,
                              hipStream_t stream)
{
    const float* x      = (const float*)d_in[0];
    const float* ln1_w  = (const float*)d_in[1];
    const float* ln2_w  = (const float*)d_in[2];
    const float* qkv_w  = (const float*)d_in[3];
    const float* off_w  = (const float*)d_in[4];
    const float* rpb    = (const float*)d_in[5];
    const float* proj_w = (const float*)d_in[6];
    const float* pi_w   = (const float*)d_in[7];
    const float* dw_w   = (const float*)d_in[8];
    const float* po_w   = (const float*)d_in[9];
    float* out = (float*)d_out;

    // ---- workspace layout (ushort units), ~137 MB ----
    ushort_t* ws = (ushort_t*)d_ws;
    ushort_t* qkv_wb  = ws;                                   // 648*192 merged
    ushort_t* proj_wb = qkv_wb  + 648 * 192;
    ushort_t* pi_wb   = proj_wb + 192 * 192;
    ushort_t* po_wb   = pi_wb   + 1024 * 192;
    ushort_t* dwT     = po_wb   + 192 * 512;                  // 9*1024
    ushort_t* dwP     = dwT     + 9 * 1024;                   // 8192 (pair words)
    ushort_t* dwS     = dwP     + 8192;                       // 1024
    ushort_t* xn      = dwS     + 1024;                       // attn-out [2][4][N][48]
    ushort_t* qkvb    = xn      + (size_t)2 * NN * CDIM;      // [2][12][N][48] (also g)
    ushort_t* offb    = qkvb    + (size_t)2 * 12 * NN * 48;   // [2][4][N][24]
    ushort_t* t       = offb    + (size_t)2 * 4 * NN * 24;    // [2][N][1024]
    ushort_t* xn2     = t       + (size_t)2 * NN * 1024;      // [2][N][192]
    ushort_t* attn    = xn;
    ushort_t* g       = qkvb;

    dim3 blk(256);

    convw_all<<<dim3((CW_TOTAL + 255) / 256), blk, 0, stream>>>(
        qkv_w, off_w, proj_w, pi_w, po_w, dw_w, ws);

    const int shm64  = 64 * 200 * 2;        // 25600 B
    const int shm128 = 128 * 200 * 2;       // 51200 B
    const int shm512 = 64 * 520 * 2;        // 66560 B
    const size_t XN_S   = (size_t)NN * CDIM;
    const size_t QKV_S  = (size_t)12 * NN * 48;
    const size_t OFF_S  = (size_t)4 * NN * 24;
    const size_t APL_S  = (size_t)4 * NN * 48;
    const size_t T_S    = (size_t)NN * 1024;
    const size_t G_S    = (size_t)NN * 512;
    const size_t CM_S   = (size_t)CDIM * NN;

    // 1. qkv planes + offsets + FUSED LN1: 768-thread blocks
    gemm_mfma<5, 2, 192, 200, 64, 768><<<dim3(256, 1, 2), dim3(768), shm64, stream>>>(
        qkv_wb, nullptr, x, qkvb, 648, CM_S, QKV_S, OFF_S, ln1_w, offb);
    // 2. deformable attention
    attn_kernel<<<dim3(2048), blk, 0, stream>>>(qkvb, offb, rpb, attn);
    // 3. x1 = x + proj_wb @ attn -> d_out, fused LN2 -> xn2
    gemm_mfma<4, 1, 192, 200, 128, 192><<<dim3(128, 1, 2), dim3(192), shm128, stream>>>(
        proj_wb, attn, x, out, 192, APL_S, CM_S, CM_S, ln2_w, xn2);
    // 4. t = pi_wb @ xn2   (operand-swapped MFMA; row-adjacent store order)
    gemm_mfma<3, 0, 192, 200, 128, 512><<<dim3(128, 2, 2), dim3(512), shm128, stream>>>(
        pi_wb, xn2, nullptr, t, 1024, XN_S, T_S, 0, nullptr, nullptr);
    // 5. g = gelu(dw(t1)) * dw(t2)  (pair-packed interior path)
    dwgate_kernel<<<dim3(NN * 64 / 256, 2), blk, 0, stream>>>(
        t, dwT, (const unsigned int*)dwP, dwS, g);
    // 6. out = x1 + po_wb @ g
    gemm_mfma<2, 0, 512, 520, 64, 192><<<dim3(256, 1, 2), dim3(192), shm512, stream>>>(
        po_wb, g, out, out, 192, G_S, CM_S, CM_S, nullptr, nullptr);
}

// Round 25
// 215.841 us; speedup vs baseline: 1.0575x; 1.0029x over previous
//
#include <hip/hip_runtime.h>
#include <math.h>

#define NN 16384      // H*W per image
#define WW 128
#define CDIM 192
#define HIDD 510
#define BB 2

typedef unsigned short ushort_t;
using short8 = __attribute__((ext_vector_type(8))) short;
using f32x4  = __attribute__((ext_vector_type(4))) float;

__device__ __forceinline__ float bf2f(ushort_t u) {
    union { unsigned int i; float f; } v; v.i = ((unsigned int)u) << 16; return v.f;
}
__device__ __forceinline__ ushort_t f2bf(float f) {
    union { unsigned int i; float f; } v; v.f = f;
    unsigned int i = v.i;
    return (ushort_t)((i + 0x7fffu + ((i >> 16) & 1u)) >> 16);  // RNE
}
// d = a.bf16[0]*b.bf16[0] + a.bf16[1]*b.bf16[1] + c   (V_DOT2_F32_BF16)
__device__ __forceinline__ float dot2bf(unsigned int a, unsigned int b, float c) {
    float d;
    asm("v_dot2_f32_bf16 %0, %1, %2, %3" : "=v"(d) : "v"(a), "v"(b), "v"(c));
    return d;
}
// pack two f32 -> bf16x2 word (lo = a, hi = b)
__device__ __forceinline__ unsigned int cvtpk(float a, float b) {
    unsigned int r;
    asm("v_cvt_pk_bf16_f32 %0, %1, %2" : "=v"(r) : "v"(a), "v"(b));
    return r;
}

// -------- ALL weight conversions in one kernel (range-dispatched) ----------
// appended: dwP [2][4 pairs][512] bf16x2-words (8192 ushorts),
//           dwS [2][512] bf16 singles for tap 8 (1024 ushorts)
#define CW_TOTAL 474624
__global__ __launch_bounds__(256) void convw_all(
    const float* __restrict__ qkv_w, const float* __restrict__ off_w,
    const float* __restrict__ proj_w, const float* __restrict__ pi_w,
    const float* __restrict__ po_w,  const float* __restrict__ dw_w,
    ushort_t* __restrict__ ws)
{
    int idx = blockIdx.x * 256 + threadIdx.x;
    if (idx >= CW_TOTAL) return;
    int i = idx;
    if (i < 110592) { ws[idx] = f2bf(qkv_w[i]); return; }
    i -= 110592;
    if (i < 13824)  { ws[idx] = f2bf(off_w[i]); return; }
    i -= 13824;
    if (i < 36864)  { ws[idx] = f2bf(proj_w[i]); return; }
    i -= 36864;
    if (i < 196608) {
        int o = i / 192, k = i - o * 192;
        bool zero = (o == 510) || (o == 511) || (o >= 1022);
        int so = (o < 510) ? o : o - 2;
        ws[idx] = zero ? (ushort_t)0 : f2bf(pi_w[(size_t)so * 192 + k]);
        return;
    }
    i -= 196608;
    if (i < 98304) {
        int o = i >> 9, k = i & 511;
        ws[idx] = (k < HIDD) ? f2bf(po_w[(size_t)o * HIDD + k]) : (ushort_t)0;
        return;
    }
    i -= 98304;
    if (i < 9216) {   // dwT: [9][2][512] (edge path)
        int p = i >> 10, c = i & 1023;
        int half = c >> 9, cc = c & 511;
        ws[idx] = (cc < HIDD) ? f2bf(dw_w[(size_t)(half * HIDD + cc) * 9 + p]) : (ushort_t)0;
        return;
    }
    i -= 9216;
    if (i < 8192) {   // dwP: pair-packed; wi = i>>1, lo/hi = i&1
        int wi = i >> 1, hl = i & 1;
        int h = wi >> 11, rem = wi & 2047;
        int k = rem >> 9, c = rem & 511;
        int pos = 2 * k + hl;
        ws[idx] = (c < HIDD) ? f2bf(dw_w[(size_t)(h * HIDD + c) * 9 + pos]) : (ushort_t)0;
        return;
    }
    i -= 8192;
    {   // dwS: tap-8 singles [2][512]
        int h = i >> 9, c = i & 511;
        ws[idx] = (c < HIDD) ? f2bf(dw_w[(size_t)(h * HIDD + c) * 9 + 8]) : (ushort_t)0;
    }
}

// ---------------- MFMA GEMM: acc[o,n] = sum_k Wb[o,k]*X_pm[n,k] ------------
// XMODE 0: X pixel-major [N][KT] bf16.
// XMODE 1: X = 4 planes [4][N][48] (KT=192), attn plane-major output.
// XMODE 2: fused BiasFree-LN1 staging from f32 channel-major x (in R, stride
//          xzs, weights in W2). NSPLIT = BDIM/NTILE channel-splits; loaded
//          x values are register-cached so x is read ONCE.
// MODE 0: bf16 out at ((o/48)*NN+n)*48 + o%48      (qkv planes)
// MODE 2: f32  out at o*NN+n, += R                 (po epilogue)
// MODE 3: bf16 out at n*1024 + o (pi -> t), OPERAND-SWAPPED MFMA:
//         D[row=n][col=o]; (ni,r) outer / mi inner store nest so the 4
//         stores filling one n-row's 128B span are temporally adjacent.
// MODE 4: f32  out at o*NN+n, += R; fused LN -> bf16 XN2[n][192] (192 thr)
// MODE 5: merged qkv+off: obase<576 -> MODE0 to Yv; >=576 -> offsets to XN2
template<int MODE, int XMODE, int KT, int KP, int NTILE, int BDIM = 256>
__global__ __launch_bounds__(BDIM) void gemm_mfma(
    const ushort_t* __restrict__ Wb,
    const ushort_t* __restrict__ X,
    const float* __restrict__ R,
    void* __restrict__ Yv,
    int O,
    size_t xzs, size_t yzs, size_t rzs,
    const float* __restrict__ W2, ushort_t* __restrict__ XN2)
{
    extern __shared__ ushort_t Xt[];   // [NTILE][KP]
    constexpr int NSEG = KT >> 3;
    constexpr int NFR  = NTILE / 16;
    int tid = threadIdx.x;
    constexpr int nt = BDIM;
    constexpr int nw = BDIM >> 6;
    int z   = blockIdx.z;
    int n0  = blockIdx.x * NTILE;

    if constexpr (XMODE == 0 || XMODE == 1) {
        const ushort_t* Xb = X + (size_t)z * xzs;
        for (int u = tid; u < NTILE * NSEG; u += nt) {
            int r = u / NSEG, seg = u - r * NSEG;
            const ushort_t* src;
            if (XMODE == 0) {
                src = Xb + (size_t)(n0 + r) * KT + seg * 8;
            } else {
                int plane = seg / 6, w8 = seg - plane * 6;
                src = Xb + ((size_t)plane * NN + n0 + r) * 48 + w8 * 8;
            }
            *(uint4*)&Xt[(size_t)r * KP + seg * 8] = *(const uint4*)src;
        }
    } else {
        // XMODE 2: fused LN1. BDIM = NSPLIT * NTILE threads; x read once,
        // values register-cached for the normalize pass.
        constexpr int NSPLIT = BDIM / NTILE;
        constexpr int CPS    = CDIM / NSPLIT;
        __shared__ float lnr[NSPLIT][NTILE][2];
        int px = tid % NTILE, cs = tid / NTILE;
        const float* xp = R + (size_t)z * xzs + (size_t)(cs * CPS) * NN + n0 + px;
        float xv[CPS];
        float s = 0.f, s2 = 0.f;
        #pragma unroll
        for (int cc = 0; cc < CPS; ++cc) {
            float v = xp[(size_t)cc * NN];
            xv[cc] = v;
            s += v; s2 += v * v;
        }
        lnr[cs][px][0] = s; lnr[cs][px][1] = s2;
        __syncthreads();
        float ts = 0.f, ts2 = 0.f;
        #pragma unroll
        for (int q = 0; q < NSPLIT; ++q) { ts += lnr[q][px][0]; ts2 += lnr[q][px][1]; }
        float mu  = ts * (1.f / 192.f);
        float rs_ = rsqrtf(ts2 * (1.f / 192.f) - mu * mu + 1e-5f);
        #pragma unroll
        for (int cc = 0; cc < CPS; cc += 2) {
            float v0 = xv[cc]     * rs_ * W2[cs * CPS + cc];
            float v1 = xv[cc + 1] * rs_ * W2[cs * CPS + cc + 1];
            unsigned int pk = (unsigned int)f2bf(v0) | ((unsigned int)f2bf(v1) << 16);
            *(unsigned int*)&Xt[(size_t)px * KP + cs * CPS + cc] = pk;
        }
    }
    __syncthreads();

    int w = tid >> 6, l = tid & 63;
    int o0w = blockIdx.y * (nw * 64) + w * 64;
    if (o0w >= O) return;

    int lrow = l & 15;
    int lk   = (l >> 4) * 8;

    f32x4 acc[4][NFR] = {};

    #pragma unroll
    for (int kk0 = 0; kk0 < KT; kk0 += 32) {
        short8 bfr[NFR];
        #pragma unroll
        for (int ni = 0; ni < NFR; ++ni)
            bfr[ni] = *(const short8*)&Xt[(size_t)(ni * 16 + lrow) * KP + kk0 + lk];
        short8 afr[4];
        #pragma unroll
        for (int mi = 0; mi < 4; ++mi) {
            int orow = o0w + mi * 16 + lrow;
            if (orow < O)
                afr[mi] = *(const short8*)(Wb + (size_t)orow * KT + kk0 + lk);
            else
                afr[mi] = short8{0,0,0,0,0,0,0,0};
        }
        #pragma unroll
        for (int mi = 0; mi < 4; ++mi)
            #pragma unroll
            for (int ni = 0; ni < NFR; ++ni) {
                if constexpr (MODE == 3)
                    // operand-swapped: D[row=n][col=o] (same dot products)
                    acc[mi][ni] = __builtin_amdgcn_mfma_f32_16x16x32_bf16(
                        bfr[ni], afr[mi], acc[mi][ni], 0, 0, 0);
                else
                    acc[mi][ni] = __builtin_amdgcn_mfma_f32_16x16x32_bf16(
                        afr[mi], bfr[ni], acc[mi][ni], 0, 0, 0);
            }
    }

    int orow0 = (l >> 4) * 4;

    if constexpr (MODE == 3) {
        // D' layout: col(lane&15) = o within tile, row((lane>>4)*4+r) = n.
        // (ni,r) outer / mi inner: the 4 mi stores fill 128B of one n-row
        // back-to-back so L2 write-combines full lines.
        int ocol  = l & 15;
        int nrow0 = (l >> 4) * 4;
        ushort_t* dstB = (ushort_t*)Yv + (size_t)z * yzs;
        #pragma unroll
        for (int ni = 0; ni < NFR; ++ni) {
            int nb = n0 + ni * 16 + nrow0;
            #pragma unroll
            for (int r = 0; r < 4; ++r) {
                ushort_t* row = dstB + (size_t)(nb + r) * 1024;
                #pragma unroll
                for (int mi = 0; mi < 4; ++mi)
                    row[o0w + mi * 16 + ocol] = f2bf(acc[mi][ni][r]);
            }
        }
    } else if constexpr (MODE == 4) {
        __shared__ float red[3][NTILE][2];
        float s[NFR] = {}, s2[NFR] = {};
        #pragma unroll
        for (int mi = 0; mi < 4; ++mi)
            #pragma unroll
            for (int ni = 0; ni < NFR; ++ni) {
                int n = n0 + ni * 16 + lrow;
                int obase = o0w + mi * 16 + orow0;
                #pragma unroll
                for (int r = 0; r < 4; ++r) {
                    float v = acc[mi][ni][r] +
                              R[(size_t)z * rzs + (size_t)(obase + r) * NN + n];
                    acc[mi][ni][r] = v;
                    s[ni] += v; s2[ni] += v * v;
                }
            }
        #pragma unroll
        for (int ni = 0; ni < NFR; ++ni) {
            s[ni]  += __shfl_xor(s[ni], 16);  s[ni]  += __shfl_xor(s[ni], 32);
            s2[ni] += __shfl_xor(s2[ni], 16); s2[ni] += __shfl_xor(s2[ni], 32);
        }
        if (l < 16) {
            #pragma unroll
            for (int ni = 0; ni < NFR; ++ni) {
                red[w][ni * 16 + l][0] = s[ni];
                red[w][ni * 16 + l][1] = s2[ni];
            }
        }
        __syncthreads();
        float rsv[NFR];
        #pragma unroll
        for (int ni = 0; ni < NFR; ++ni) {
            int nl = ni * 16 + lrow;
            float ts  = red[0][nl][0] + red[1][nl][0] + red[2][nl][0];
            float ts2 = red[0][nl][1] + red[1][nl][1] + red[2][nl][1];
            float mu  = ts * (1.f / 192.f);
            float var = ts2 * (1.f / 192.f) - mu * mu;
            rsv[ni] = rsqrtf(var + 1e-5f);
        }
        #pragma unroll
        for (int mi = 0; mi < 4; ++mi)
            #pragma unroll
            for (int ni = 0; ni < NFR; ++ni) {
                int n = n0 + ni * 16 + lrow;
                int obase = o0w + mi * 16 + orow0;
                #pragma unroll
                for (int r = 0; r < 4; ++r)
                    ((float*)Yv)[(size_t)z * yzs + (size_t)(obase + r) * NN + n]
                        = acc[mi][ni][r];
                float rs_ = rsv[ni];
                unsigned int lo =
                    (unsigned int)f2bf(acc[mi][ni][0] * rs_ * W2[obase])
                  | ((unsigned int)f2bf(acc[mi][ni][1] * rs_ * W2[obase + 1]) << 16);
                unsigned int hi =
                    (unsigned int)f2bf(acc[mi][ni][2] * rs_ * W2[obase + 2])
                  | ((unsigned int)f2bf(acc[mi][ni][3] * rs_ * W2[obase + 3]) << 16);
                *(uint2*)(XN2 + (size_t)z * ((size_t)NN * CDIM)
                          + (size_t)n * CDIM + obase) = make_uint2(lo, hi);
            }
    } else {
        #pragma unroll
        for (int mi = 0; mi < 4; ++mi) {
            #pragma unroll
            for (int ni = 0; ni < NFR; ++ni) {
                int n = n0 + ni * 16 + lrow;
                int obase = o0w + mi * 16 + orow0;
                float v0 = acc[mi][ni][0], v1 = acc[mi][ni][1];
                float v2 = acc[mi][ni][2], v3 = acc[mi][ni][3];
                if (MODE == 0) {
                    if (obase >= O) continue;
                    unsigned int lo = (unsigned int)f2bf(v0) | ((unsigned int)f2bf(v1) << 16);
                    unsigned int hi = (unsigned int)f2bf(v2) | ((unsigned int)f2bf(v3) << 16);
                    size_t base = ((size_t)(obase / 48) * NN + n) * 48 + (obase % 48);
                    *(uint2*)((ushort_t*)Yv + (size_t)z * yzs + base) = make_uint2(lo, hi);
                } else if (MODE == 5) {
                    if (obase < 576) {
                        unsigned int lo = (unsigned int)f2bf(v0) | ((unsigned int)f2bf(v1) << 16);
                        unsigned int hi = (unsigned int)f2bf(v2) | ((unsigned int)f2bf(v3) << 16);
                        size_t base = ((size_t)(obase / 48) * NN + n) * 48 + (obase % 48);
                        *(uint2*)((ushort_t*)Yv + (size_t)z * yzs + base) = make_uint2(lo, hi);
                    } else {
                        float vv[4] = {v0, v1, v2, v3};
                        #pragma unroll
                        for (int r = 0; r < 4; ++r) {
                            int o = obase + r - 576;
                            if (o >= 0 && o < 72)
                                XN2[(size_t)z * rzs +
                                    ((size_t)(o / 18) * NN + n) * 24 + (o % 18)] = f2bf(vv[r]);
                        }
                    }
                } else {  // MODE 2
                    float vv[4] = {v0, v1, v2, v3};
                    #pragma unroll
                    for (int r = 0; r < 4; ++r) {
                        int o = obase + r;
                        if (o < O) {
                            size_t idx = (size_t)o * NN + n;
                            ((float*)Yv)[(size_t)z * yzs + idx] = vv[r] + R[(size_t)z * rzs + idx];
                        }
                    }
                }
            }
        }
    }
}

// ------------- deformable attention, single dispatch, XCD-bijective --------
__global__ __launch_bounds__(256, 2) void attn_kernel(
    const ushort_t* __restrict__ qkv_pm,   // [B][12][N][48]
    const ushort_t* __restrict__ off_pm,   // [B][4][N][24]
    const float* __restrict__ rpb,         // [4,9]
    ushort_t* __restrict__ out_pl)         // [B][4][N][48]
{
    int bid = blockIdx.x;                       // 0..2047
    int lin = (bid & 7) * 256 + (bid >> 3);
    int c   = lin >> 7;                         // 0..15
    int b   = c >> 3;
    int h   = (c >> 1) & 3;
    int half= c & 1;
    int r   = lin & 127;
    int py  = half * 64 + (r >> 1);
    int tid = threadIdx.x;
    int px  = (r & 1) * 64 + (tid >> 2);
    int s   = tid & 3;
    int n   = py * WW + px;

    const ushort_t* qkvB = qkv_pm + (size_t)b * 12 * NN * 48;
    const ushort_t* offB = off_pm + (size_t)b * 4 * NN * 24;
    ushort_t*       outB = out_pl + (size_t)b * 4 * NN * 48;

    union { uint4 u[3]; ushort_t v[24]; } ob;
    {
        const ushort_t* op = offB + ((size_t)h * NN + n) * 24;
        ob.u[0] = *(const uint4*)op;
        ob.u[1] = *(const uint4*)(op + 8);
        ob.u[2] = *(const uint4*)(op + 16);
    }

    int   baseu[9], dxu[9], dyu[9];
    float wyA[9], wxA[9];
    #pragma unroll
    for (int kpt = 0; kpt < 9; ++kpt) {
        float oy = bf2f(ob.v[kpt * 2 + 0]);
        float ox = bf2f(ob.v[kpt * 2 + 1]);
        float cy = fminf(fmaxf((float)(py + (kpt / 3) - 1) + oy, 0.f), 127.f);
        float cx = fminf(fmaxf((float)(px + (kpt % 3) - 1) + ox, 0.f), 127.f);
        float y0f = floorf(cy), x0f = floorf(cx);
        wyA[kpt] = cy - y0f; wxA[kpt] = cx - x0f;
        int y0 = (int)y0f, x0 = (int)x0f;
        baseu[kpt] = (y0 * WW + x0) * 48;
        dxu[kpt]   = (x0 < 127) ? 48 : 0;
        dyu[kpt]   = (y0 < 127) ? (WW * 48) : 0;
    }

    const ushort_t* qrow  = qkvB + ((size_t)h * NN + n) * 48;
    const ushort_t* kbase = qkvB + ((size_t)(4 + h) * NN) * 48;
    const ushort_t* vbase = qkvB + ((size_t)(8 + h) * NN) * 48;
    int co0 = s * 12;

    unsigned int qp[6];
    {
        uint2 a = *(const uint2*)(qrow + co0);
        uint2 bq = *(const uint2*)(qrow + co0 + 4);
        uint2 cq = *(const uint2*)(qrow + co0 + 8);
        qp[0] = a.x; qp[1] = a.y; qp[2] = bq.x; qp[3] = bq.y; qp[4] = cq.x; qp[5] = cq.y;
    }

    float logits[9];
    #pragma unroll
    for (int kpt = 0; kpt < 9; ++kpt) {
        const ushort_t* kb = kbase + baseu[kpt] + co0;
        int du = dxu[kpt], dv = dyu[kpt];
        float d0 = 0.f, d1 = 0.f, d2 = 0.f, d3 = 0.f;
        #pragma unroll
        for (int ch = 0; ch < 3; ++ch) {
            const ushort_t* p = kb + ch * 4;
            uint2 k0 = *(const uint2*)p;
            uint2 k1 = *(const uint2*)(p + du);
            uint2 k2 = *(const uint2*)(p + dv);
            uint2 k3 = *(const uint2*)(p + dv + du);
            d0 = dot2bf(k0.x, qp[2 * ch], d0); d0 = dot2bf(k0.y, qp[2 * ch + 1], d0);
            d1 = dot2bf(k1.x, qp[2 * ch], d1); d1 = dot2bf(k1.y, qp[2 * ch + 1], d1);
            d2 = dot2bf(k2.x, qp[2 * ch], d2); d2 = dot2bf(k2.y, qp[2 * ch + 1], d2);
            d3 = dot2bf(k3.x, qp[2 * ch], d3); d3 = dot2bf(k3.y, qp[2 * ch + 1], d3);
        }
        float wy = wyA[kpt], wx = wxA[kpt];
        float iy = 1.f - wy, ix = 1.f - wx;
        logits[kpt] = fmaf(wy * wx, d3, fmaf(wy * ix, d2,
                      fmaf(iy * wx, d1, iy * ix * d0)));
    }

    #pragma unroll
    for (int kpt = 0; kpt < 9; ++kpt) {
        float v = logits[kpt];
        v += __shfl_xor(v, 1);
        v += __shfl_xor(v, 2);
        logits[kpt] = v * 0.14433756729740643f + rpb[h * 9 + kpt];
    }
    float m = logits[0];
    #pragma unroll
    for (int i = 1; i < 9; ++i) m = fmaxf(m, logits[i]);
    float ssum = 0.f;
    #pragma unroll
    for (int i = 0; i < 9; ++i) { logits[i] = __expf(logits[i] - m); ssum += logits[i]; }
    float inv = 1.f / ssum;

    float oacc[12] = {};
    #pragma unroll
    for (int kpt = 0; kpt < 9; ++kpt) {
        float wy = wyA[kpt], wx = wxA[kpt];
        float iy = 1.f - wy, ix = 1.f - wx;
        float a = logits[kpt] * inv;
        unsigned int w01 = cvtpk(a * iy * ix, a * iy * wx);
        unsigned int w23 = cvtpk(a * wy * ix, a * wy * wx);
        const ushort_t* vb = vbase + baseu[kpt] + co0;
        int du = dxu[kpt], dv = dyu[kpt];
        #pragma unroll
        for (int ch = 0; ch < 3; ++ch) {
            const ushort_t* p = vb + ch * 4;
            uint2 A = *(const uint2*)p;
            uint2 Bv = *(const uint2*)(p + du);
            uint2 Cv = *(const uint2*)(p + dv);
            uint2 Dv = *(const uint2*)(p + dv + du);
            unsigned int T0 = __builtin_amdgcn_perm(A.x, Bv.x, 0x01000504u);
            unsigned int T1 = __builtin_amdgcn_perm(A.x, Bv.x, 0x03020706u);
            unsigned int U0 = __builtin_amdgcn_perm(Cv.x, Dv.x, 0x01000504u);
            unsigned int U1 = __builtin_amdgcn_perm(Cv.x, Dv.x, 0x03020706u);
            oacc[ch * 4 + 0] = dot2bf(U0, w23, dot2bf(T0, w01, oacc[ch * 4 + 0]));
            oacc[ch * 4 + 1] = dot2bf(U1, w23, dot2bf(T1, w01, oacc[ch * 4 + 1]));
            T0 = __builtin_amdgcn_perm(A.y, Bv.y, 0x01000504u);
            T1 = __builtin_amdgcn_perm(A.y, Bv.y, 0x03020706u);
            U0 = __builtin_amdgcn_perm(Cv.y, Dv.y, 0x01000504u);
            U1 = __builtin_amdgcn_perm(Cv.y, Dv.y, 0x03020706u);
            oacc[ch * 4 + 2] = dot2bf(U0, w23, dot2bf(T0, w01, oacc[ch * 4 + 2]));
            oacc[ch * 4 + 3] = dot2bf(U1, w23, dot2bf(T1, w01, oacc[ch * 4 + 3]));
        }
    }

    ushort_t* orow = outB + ((size_t)h * NN + n) * 48 + co0;
    #pragma unroll
    for (int ch = 0; ch < 3; ++ch) {
        unsigned int lo = (unsigned int)f2bf(oacc[ch * 4 + 0])
                        | ((unsigned int)f2bf(oacc[ch * 4 + 1]) << 16);
        unsigned int hi = (unsigned int)f2bf(oacc[ch * 4 + 2])
                        | ((unsigned int)f2bf(oacc[ch * 4 + 3]) << 16);
        *(uint2*)(orow + ch * 4) = make_uint2(lo, hi);
    }
}

// ------- depthwise 3x3 (both halves) + exact-GELU gate; 8 ch / thread ------
// Wave = one pixel -> interior/edge branch is wave-uniform.
// Interior: 4 tap-pairs via v_perm + prepacked bf16x2 weights + dot2.
__global__ __launch_bounds__(256) void dwgate_kernel(
    const ushort_t* __restrict__ t_pm,
    const ushort_t* __restrict__ wT,    // [9][2][512] (edge path)
    const unsigned int* __restrict__ wP,// [2][4][512] packed pairs
    const ushort_t* __restrict__ wS,    // [2][512] tap-8 singles
    ushort_t* __restrict__ g_pm)
{
    int b = blockIdx.y;
    const ushort_t* tB = t_pm + (size_t)b * NN * 1024;
    ushort_t*       gB = g_pm + (size_t)b * NN * 512;
    int bid = blockIdx.x;                        // 4096
    int lin = (bid & 7) * 512 + (bid >> 3);      // XCD-contiguous
    int idx = lin * 256 + threadIdx.x;           // over N*64
    int c0 = (idx & 63) * 8;
    int n  = idx >> 6;
    int y = n >> 7, x = n & 127;
    float a1[8] = {}, a2[8] = {};

    if (x >= 1 && x <= 126 && y >= 1 && y <= 126) {
        // ---- interior fast path: 4 pairs + 1 single per half ----
        const ushort_t* trow[9];
        #pragma unroll
        for (int p = 0; p < 9; ++p)
            trow[p] = tB + (size_t)((y + p / 3 - 1) * WW + (x + p % 3 - 1)) * 1024;
        #pragma unroll
        for (int hlf = 0; hlf < 2; ++hlf) {
            float* aa = hlf ? a2 : a1;
            int cb = c0 + hlf * 512;
            #pragma unroll
            for (int k = 0; k < 4; ++k) {
                uint4 A = *(const uint4*)(trow[2 * k] + cb);
                uint4 Bv = *(const uint4*)(trow[2 * k + 1] + cb);
                uint4 W0 = *(const uint4*)(wP + (size_t)(hlf * 4 + k) * 512 + c0);
                uint4 W1 = *(const uint4*)(wP + (size_t)(hlf * 4 + k) * 512 + c0 + 4);
                unsigned int Av[4] = {A.x, A.y, A.z, A.w};
                unsigned int Bw[4] = {Bv.x, Bv.y, Bv.z, Bv.w};
                unsigned int Wv[8] = {W0.x, W0.y, W0.z, W0.w, W1.x, W1.y, W1.z, W1.w};
                #pragma unroll
                for (int d = 0; d < 4; ++d) {
                    unsigned int T0 = __builtin_amdgcn_perm(Av[d], Bw[d], 0x01000504u);
                    unsigned int T1 = __builtin_amdgcn_perm(Av[d], Bw[d], 0x03020706u);
                    aa[2 * d]     = dot2bf(T0, Wv[2 * d],     aa[2 * d]);
                    aa[2 * d + 1] = dot2bf(T1, Wv[2 * d + 1], aa[2 * d + 1]);
                }
            }
            {   // single tap 8 (dy=+1, dx=+1)
                short8 tv = *(const short8*)(trow[8] + cb);
                short8 wv = *(const short8*)(wS + hlf * 512 + c0);
                #pragma unroll
                for (int j = 0; j < 8; ++j)
                    aa[j] = fmaf(bf2f((ushort_t)tv[j]), bf2f((ushort_t)wv[j]), aa[j]);
            }
        }
    } else {
        // ---- edge path: original scalar taps with bounds checks ----
        #pragma unroll
        for (int dy = 0; dy < 3; ++dy) {
            int yy = y + dy - 1;
            if (yy < 0 || yy > 127) continue;
            #pragma unroll
            for (int dx = 0; dx < 3; ++dx) {
                int xx = x + dx - 1;
                if (xx < 0 || xx > 127) continue;
                int p = dy * 3 + dx;
                const ushort_t* tr = tB + (size_t)(yy * WW + xx) * 1024;
                short8 t1 = *(const short8*)(tr + c0);
                short8 t2 = *(const short8*)(tr + 512 + c0);
                short8 w1 = *(const short8*)(wT + p * 1024 + c0);
                short8 w2 = *(const short8*)(wT + p * 1024 + 512 + c0);
                #pragma unroll
                for (int j = 0; j < 8; ++j) {
                    a1[j] = fmaf(bf2f((ushort_t)t1[j]), bf2f((ushort_t)w1[j]), a1[j]);
                    a2[j] = fmaf(bf2f((ushort_t)t2[j]), bf2f((ushort_t)w2[j]), a2[j]);
                }
            }
        }
    }
    short8 o8;
    #pragma unroll
    for (int j = 0; j < 8; ++j) {
        float ge = 0.5f * a1[j] * (1.f + erff(a1[j] * 0.70710678118654752f));
        o8[j] = (short)f2bf(ge * a2[j]);
    }
    *(short8*)(gB + (size_t)n * 512 + c0) = o8;
}

extern "C" void kernel_launch(void* const* d_in, const int* in_sizes, int n_in,
                              void* d_out, int out_size, void* d_ws, size_t ws_size,
                              hipStream_t stream)
{
    const float* x      = (const float*)d_in[0];
    const float* ln1_w  = (const float*)d_in[1];
    const float* ln2_w  = (const float*)d_in[2];
    const float* qkv_w  = (const float*)d_in[3];
    const float* off_w  = (const float*)d_in[4];
    const float* rpb    = (const float*)d_in[5];
    const float* proj_w = (const float*)d_in[6];
    const float* pi_w   = (const float*)d_in[7];
    const float* dw_w   = (const float*)d_in[8];
    const float* po_w   = (const float*)d_in[9];
    float* out = (float*)d_out;

    // ---- workspace layout (ushort units), ~137 MB ----
    ushort_t* ws = (ushort_t*)d_ws;
    ushort_t* qkv_wb  = ws;                                   // 648*192 merged
    ushort_t* proj_wb = qkv_wb  + 648 * 192;
    ushort_t* pi_wb   = proj_wb + 192 * 192;
    ushort_t* po_wb   = pi_wb   + 1024 * 192;
    ushort_t* dwT     = po_wb   + 192 * 512;                  // 9*1024
    ushort_t* dwP     = dwT     + 9 * 1024;                   // 8192 (pair words)
    ushort_t* dwS     = dwP     + 8192;                       // 1024
    ushort_t* xn      = dwS     + 1024;                       // attn-out [2][4][N][48]
    ushort_t* qkvb    = xn      + (size_t)2 * NN * CDIM;      // [2][12][N][48] (also g)
    ushort_t* offb    = qkvb    + (size_t)2 * 12 * NN * 48;   // [2][4][N][24]
    ushort_t* t       = offb    + (size_t)2 * 4 * NN * 24;    // [2][N][1024]
    ushort_t* xn2     = t       + (size_t)2 * NN * 1024;      // [2][N][192]
    ushort_t* attn    = xn;
    ushort_t* g       = qkvb;

    dim3 blk(256);

    convw_all<<<dim3((CW_TOTAL + 255) / 256), blk, 0, stream>>>(
        qkv_w, off_w, proj_w, pi_w, po_w, dw_w, ws);

    const int shm64  = 64 * 200 * 2;        // 25600 B
    const int shm128 = 128 * 200 * 2;       // 51200 B
    const int shm512 = 64 * 520 * 2;        // 66560 B
    const size_t XN_S   = (size_t)NN * CDIM;
    const size_t QKV_S  = (size_t)12 * NN * 48;
    const size_t OFF_S  = (size_t)4 * NN * 24;
    const size_t APL_S  = (size_t)4 * NN * 48;
    const size_t T_S    = (size_t)NN * 1024;
    const size_t G_S    = (size_t)NN * 512;
    const size_t CM_S   = (size_t)CDIM * NN;

    // 1. qkv planes + offsets + FUSED LN1: 768-thread blocks, x read once
    gemm_mfma<5, 2, 192, 200, 64, 768><<<dim3(256, 1, 2), dim3(768), shm64, stream>>>(
        qkv_wb, nullptr, x, qkvb, 648, CM_S, QKV_S, OFF_S, ln1_w, offb);
    // 2. deformable attention
    attn_kernel<<<dim3(2048), blk, 0, stream>>>(qkvb, offb, rpb, attn);
    // 3. x1 = x + proj_wb @ attn -> d_out, fused LN2 -> xn2
    gemm_mfma<4, 1, 192, 200, 128, 192><<<dim3(128, 1, 2), dim3(192), shm128, stream>>>(
        proj_wb, attn, x, out, 192, APL_S, CM_S, CM_S, ln2_w, xn2);
    // 4. t = pi_wb @ xn2   (operand-swapped MFMA; row-adjacent store order)
    gemm_mfma<3, 0, 192, 200, 128, 512><<<dim3(128, 2, 2), dim3(512), shm128, stream>>>(
        pi_wb, xn2, nullptr, t, 1024, XN_S, T_S, 0, nullptr, nullptr);
    // 5. g = gelu(dw(t1)) * dw(t2)  (pair-packed interior path)
    dwgate_kernel<<<dim3(NN * 64 / 256, 2), blk, 0, stream>>>(
        t, dwT, (const unsigned int*)dwP, dwS, g);
    // 6. out = x1 + po_wb @ g
    gemm_mfma<2, 0, 512, 520, 64, 192><<<dim3(256, 1, 2), dim3(192), shm512, stream>>>(
        po_wb, g, out, out, 192, G_S, CM_S, CM_S, nullptr, nullptr);
}